// Round 1
// baseline (1650.776 us; speedup 1.0000x reference)
//
#include <hip/hip_runtime.h>
#include <math.h>

#define CCH 96
#define HH 112
#define WW 112
#define HWSZ 12544      // 112*112
#define NB 32           // batch
#define NBLK 49         // blocks per image: 12544/256
#define EPSV 1e-5f

__device__ __forceinline__ float gelu_f(float x) {
    return 0.5f * x * (1.0f + erff(x * 0.70710678118654752f));
}

// ---------------- K1: conv1x1 (x,w1,b1) -> h1, + per-block GN1 partials ----
__global__ __launch_bounds__(256) void k_conv1(
        const float* __restrict__ x, const float* __restrict__ w1,
        const float* __restrict__ b1, float* __restrict__ h1,
        float* __restrict__ part) {
    const int b = blockIdx.y;
    const int hw = blockIdx.x * 256 + threadIdx.x;
    const float* xp = x + (size_t)b * CCH * HWSZ + hw;
    float v[CCH];
    #pragma unroll
    for (int c = 0; c < CCH; ++c) v[c] = xp[(size_t)c * HWSZ];

    float* hp = h1 + (size_t)b * CCH * HWSZ + hw;
    float sum = 0.f, sumsq = 0.f;
    for (int o = 0; o < CCH; ++o) {
        const float* wr = w1 + o * CCH;
        float a0 = b1[o], a1 = 0.f;
        #pragma unroll
        for (int c = 0; c < CCH; c += 2) {
            a0 += v[c] * wr[c];
            a1 += v[c + 1] * wr[c + 1];
        }
        float a = a0 + a1;
        hp[(size_t)o * HWSZ] = a;
        sum += a;
        sumsq += a * a;
    }
    // block reduction (deterministic)
    #pragma unroll
    for (int off = 32; off > 0; off >>= 1) {
        sum += __shfl_down(sum, off);
        sumsq += __shfl_down(sumsq, off);
    }
    __shared__ float ls[8];
    const int wid = threadIdx.x >> 6, lane = threadIdx.x & 63;
    if (lane == 0) { ls[wid] = sum; ls[4 + wid] = sumsq; }
    __syncthreads();
    if (threadIdx.x == 0) {
        float s = ls[0] + ls[1] + ls[2] + ls[3];
        float q = ls[4] + ls[5] + ls[6] + ls[7];
        part[(b * NBLK + blockIdx.x) * 2 + 0] = s;
        part[(b * NBLK + blockIdx.x) * 2 + 1] = q;
    }
}

// ---------------- K2/K4: finalize GN stats -> per-(b,c) scale/shift --------
__global__ void k_stats(const float* __restrict__ part,
                        const float* __restrict__ gw, const float* __restrict__ gb,
                        float* __restrict__ sc, float* __restrict__ sh) {
    const int b = blockIdx.x;
    __shared__ float mean_s, inv_s;
    if (threadIdx.x == 0) {
        float s = 0.f, q = 0.f;
        for (int i = 0; i < NBLK; ++i) {
            s += part[(b * NBLK + i) * 2 + 0];
            q += part[(b * NBLK + i) * 2 + 1];
        }
        const float n = (float)CCH * (float)HWSZ;
        float mu = s / n;
        float var = q / n - mu * mu;
        mean_s = mu;
        inv_s = rsqrtf(var + EPSV);
    }
    __syncthreads();
    const int c = threadIdx.x;
    if (c < CCH) {
        float scale = inv_s * gw[c];
        sc[b * CCH + c] = scale;
        sh[b * CCH + c] = gb[c] - mean_s * scale;
    }
}

// ---------------- K3: gn1+gelu+shift -> conv21/conv22 -> gelu+add -> h2 ----
__global__ __launch_bounds__(256) void k_mid(
        const float* __restrict__ h1,
        const float* __restrict__ w21, const float* __restrict__ b21,
        const float* __restrict__ w22, const float* __restrict__ b22,
        const float* __restrict__ sc, const float* __restrict__ sh,
        float* __restrict__ h2, float* __restrict__ part) {
    const int b = blockIdx.y;
    const int hw = blockIdx.x * 256 + threadIdx.x;
    const int h = hw / WW, w = hw % WW;
    const float* base = h1 + (size_t)b * CCH * HWSZ;
    const float* scb = sc + b * CCH;
    const float* shb = sh + b * CCH;

    float vlr[CCH], vtd[CCH];
    // chunk 0 (c 0..31): shift s=-1 -> out[w] = in[w+1] (LR), out[h] = in[h+1] (TD)
    #pragma unroll
    for (int c = 0; c < 32; ++c) {
        vlr[c] = (w + 1 < WW) ? gelu_f(base[(size_t)c * HWSZ + hw + 1] * scb[c] + shb[c]) : 0.f;
        vtd[c] = (h + 1 < HH) ? gelu_f(base[(size_t)c * HWSZ + hw + WW] * scb[c] + shb[c]) : 0.f;
    }
    // chunk 1 (c 32..63): center
    #pragma unroll
    for (int c = 32; c < 64; ++c) {
        float g = gelu_f(base[(size_t)c * HWSZ + hw] * scb[c] + shb[c]);
        vlr[c] = g;
        vtd[c] = g;
    }
    // chunk 2 (c 64..95): shift s=+1 -> in[w-1] / in[h-1]
    #pragma unroll
    for (int c = 64; c < CCH; ++c) {
        vlr[c] = (w - 1 >= 0) ? gelu_f(base[(size_t)c * HWSZ + hw - 1] * scb[c] + shb[c]) : 0.f;
        vtd[c] = (h - 1 >= 0) ? gelu_f(base[(size_t)c * HWSZ + hw - WW] * scb[c] + shb[c]) : 0.f;
    }

    float* hp = h2 + (size_t)b * CCH * HWSZ + hw;
    float sum = 0.f, sumsq = 0.f;
    for (int o = 0; o < CCH; ++o) {
        const float* wr1 = w21 + o * CCH;
        const float* wr2 = w22 + o * CCH;
        float a0 = b21[o], a1 = 0.f;
        float c0 = b22[o], c1 = 0.f;
        #pragma unroll
        for (int c = 0; c < CCH; c += 2) {
            a0 += vlr[c] * wr1[c];
            a1 += vlr[c + 1] * wr1[c + 1];
            c0 += vtd[c] * wr2[c];
            c1 += vtd[c + 1] * wr2[c + 1];
        }
        float r = gelu_f(a0 + a1) + gelu_f(c0 + c1);
        hp[(size_t)o * HWSZ] = r;
        sum += r;
        sumsq += r * r;
    }
    #pragma unroll
    for (int off = 32; off > 0; off >>= 1) {
        sum += __shfl_down(sum, off);
        sumsq += __shfl_down(sumsq, off);
    }
    __shared__ float ls[8];
    const int wid = threadIdx.x >> 6, lane = threadIdx.x & 63;
    if (lane == 0) { ls[wid] = sum; ls[4 + wid] = sumsq; }
    __syncthreads();
    if (threadIdx.x == 0) {
        float s = ls[0] + ls[1] + ls[2] + ls[3];
        float q = ls[4] + ls[5] + ls[6] + ls[7];
        part[(b * NBLK + blockIdx.x) * 2 + 0] = s;
        part[(b * NBLK + blockIdx.x) * 2 + 1] = q;
    }
}

// ---------------- K5: gn2 + conv3 -> out -----------------------------------
__global__ __launch_bounds__(256) void k_out(
        const float* __restrict__ h2, const float* __restrict__ w3,
        const float* __restrict__ b3, const float* __restrict__ sc2,
        const float* __restrict__ sh2, float* __restrict__ out) {
    const int b = blockIdx.y;
    const int hw = blockIdx.x * 256 + threadIdx.x;
    const float* hp = h2 + (size_t)b * CCH * HWSZ + hw;
    const float* scb = sc2 + b * CCH;
    const float* shb = sh2 + b * CCH;
    float v[CCH];
    #pragma unroll
    for (int c = 0; c < CCH; ++c) v[c] = hp[(size_t)c * HWSZ] * scb[c] + shb[c];

    float* op = out + (size_t)b * CCH * HWSZ + hw;
    for (int o = 0; o < CCH; ++o) {
        const float* wr = w3 + o * CCH;
        float a0 = b3[o], a1 = 0.f;
        #pragma unroll
        for (int c = 0; c < CCH; c += 2) {
            a0 += v[c] * wr[c];
            a1 += v[c + 1] * wr[c + 1];
        }
        op[(size_t)o * HWSZ] = a0 + a1;
    }
}

extern "C" void kernel_launch(void* const* d_in, const int* in_sizes, int n_in,
                              void* d_out, int out_size, void* d_ws, size_t ws_size,
                              hipStream_t stream) {
    const float* x    = (const float*)d_in[0];
    const float* w1   = (const float*)d_in[1];
    const float* b1   = (const float*)d_in[2];
    const float* w21  = (const float*)d_in[3];
    const float* b21  = (const float*)d_in[4];
    const float* w22  = (const float*)d_in[5];
    const float* b22  = (const float*)d_in[6];
    const float* w3   = (const float*)d_in[7];
    const float* b3   = (const float*)d_in[8];
    const float* gn1w = (const float*)d_in[9];
    const float* gn1b = (const float*)d_in[10];
    const float* gn2w = (const float*)d_in[11];
    const float* gn2b = (const float*)d_in[12];

    float* out = (float*)d_out;
    float* ws  = (float*)d_ws;

    float* part1 = ws;              // 3136 floats
    float* sc1   = ws + 4096;       // 3072
    float* sh1   = ws + 8192;       // 3072
    float* part2 = ws + 12288;      // 3136
    float* sc2   = ws + 16384;      // 3072
    float* sh2   = ws + 20480;      // 3072
    float* h2    = ws + 24576;      // 38535168 floats
    float* h1    = out;             // stage conv1 output in d_out (dead until K5)

    dim3 grid(NBLK, NB), blk(256);
    k_conv1<<<grid, blk, 0, stream>>>(x, w1, b1, h1, part1);
    k_stats<<<dim3(NB), dim3(128), 0, stream>>>(part1, gn1w, gn1b, sc1, sh1);
    k_mid<<<grid, blk, 0, stream>>>(h1, w21, b21, w22, b22, sc1, sh1, h2, part2);
    k_stats<<<dim3(NB), dim3(128), 0, stream>>>(part2, gn2w, gn2b, sc2, sh2);
    k_out<<<grid, blk, 0, stream>>>(h2, w3, b3, sc2, sh2, out);
}

// Round 2
// 936.935 us; speedup vs baseline: 1.7619x; 1.7619x over previous
//
#include <hip/hip_runtime.h>
#include <math.h>

#define CCH 96
#define HH 112
#define WW 112
#define HWSZ 12544      // 112*112
#define NB 32           // batch
#define PIX 64          // pixels per block
#define NBLK 196        // blocks per image: 12544/64
#define EPSV 1e-5f

__device__ __forceinline__ float gelu_f(float x) {
    return 0.5f * x * (1.0f + erff(x * 0.70710678118654752f));
}

__device__ __forceinline__ void block_reduce_write(float sum, float sumsq,
                                                   float* part, int slot) {
    #pragma unroll
    for (int off = 32; off > 0; off >>= 1) {
        sum += __shfl_down(sum, off);
        sumsq += __shfl_down(sumsq, off);
    }
    __shared__ float ls[8];
    const int wid = threadIdx.x >> 6, lane = threadIdx.x & 63;
    if (lane == 0) { ls[wid] = sum; ls[4 + wid] = sumsq; }
    __syncthreads();
    if (threadIdx.x == 0) {
        part[slot * 2 + 0] = ls[0] + ls[1] + ls[2] + ls[3];
        part[slot * 2 + 1] = ls[4] + ls[5] + ls[6] + ls[7];
    }
}

// ---------------- K1: conv1x1 (x,w1,b1) -> h1, + per-block GN1 partials ----
__global__ __launch_bounds__(256) void k_conv1(
        const float* __restrict__ x, const float* __restrict__ w1,
        const float* __restrict__ b1, float* __restrict__ h1,
        float* __restrict__ part) {
    __shared__ float sv[CCH][PIX];
    const int b = blockIdx.y;
    const int hw0 = blockIdx.x * PIX;
    const int wid = __builtin_amdgcn_readfirstlane(threadIdx.x >> 6);
    const int lane = threadIdx.x & 63;

    const float* xb = x + (size_t)b * CCH * HWSZ + hw0;
    #pragma unroll
    for (int i = 0; i < 24; ++i) {
        const int c = i * 4 + wid;
        sv[c][lane] = xb[(size_t)c * HWSZ + lane];
    }
    __syncthreads();

    const int ob = wid * 24;
    float acc[24];
    #pragma unroll
    for (int oo = 0; oo < 24; ++oo) acc[oo] = b1[ob + oo];
    #pragma unroll 4
    for (int c = 0; c < CCH; ++c) {
        const float v = sv[c][lane];
        #pragma unroll
        for (int oo = 0; oo < 24; ++oo)
            acc[oo] = fmaf(v, w1[(ob + oo) * CCH + c], acc[oo]);
    }

    float* hb = h1 + (size_t)b * CCH * HWSZ + hw0 + lane;
    float sum = 0.f, sumsq = 0.f;
    #pragma unroll
    for (int oo = 0; oo < 24; ++oo) {
        const float a = acc[oo];
        hb[(size_t)(ob + oo) * HWSZ] = a;
        sum += a;
        sumsq += a * a;
    }
    block_reduce_write(sum, sumsq, part, b * NBLK + blockIdx.x);
}

// ---------------- finalize GN stats -> (mean, rsqrt(var+eps)) per sample ---
__global__ void k_stats(const float* __restrict__ part, float* __restrict__ ms) {
    const int b = blockIdx.x;
    const int t = threadIdx.x;  // 64
    float s = 0.f, q = 0.f;
    for (int i = t; i < NBLK; i += 64) {
        s += part[(b * NBLK + i) * 2 + 0];
        q += part[(b * NBLK + i) * 2 + 1];
    }
    #pragma unroll
    for (int off = 32; off > 0; off >>= 1) {
        s += __shfl_down(s, off);
        q += __shfl_down(q, off);
    }
    if (t == 0) {
        const float n = (float)CCH * (float)HWSZ;
        const float mu = s / n;
        const float var = q / n - mu * mu;
        ms[2 * b + 0] = mu;
        ms[2 * b + 1] = rsqrtf(var + EPSV);
    }
}

// ---------------- K3: gn1+gelu+shift -> conv21/conv22 -> gelu+add -> h2 ----
__global__ __launch_bounds__(256) void k_mid(
        const float* __restrict__ h1,
        const float* __restrict__ w21, const float* __restrict__ b21,
        const float* __restrict__ w22, const float* __restrict__ b22,
        const float* __restrict__ ms1,
        const float* __restrict__ gw, const float* __restrict__ gb,
        float* __restrict__ h2, float* __restrict__ part) {
    __shared__ float s_vlr[CCH][PIX];
    __shared__ float s_vtd[CCH][PIX];
    const int b = blockIdx.y;
    const int hw0 = blockIdx.x * PIX;
    const int wid = __builtin_amdgcn_readfirstlane(threadIdx.x >> 6);
    const int lane = threadIdx.x & 63;

    const float mu = ms1[2 * b + 0];
    const float inv = ms1[2 * b + 1];
    const float* hb = h1 + (size_t)b * CCH * HWSZ;

    const int hw = hw0 + lane;
    const int h = hw / WW, w = hw % WW;

    #pragma unroll
    for (int i = 0; i < 24; ++i) {
        const int c = i * 4 + wid;
        const int chunk = c >> 5;           // 0,1,2
        const int d = (chunk == 0) ? 1 : (chunk == 2) ? -1 : 0;  // src offset
        const float scale = inv * gw[c];
        const float shift = gb[c] - mu * scale;
        // LR: read (h, w+d)
        const int wl = w + d;
        float vl = 0.f;
        if (wl >= 0 && wl < WW)
            vl = gelu_f(hb[(size_t)c * HWSZ + hw + d] * scale + shift);
        s_vlr[c][lane] = vl;
        // TD: read (h+d, w)
        const int ht = h + d;
        float vt = 0.f;
        if (ht >= 0 && ht < HH)
            vt = gelu_f(hb[(size_t)c * HWSZ + hw + d * WW] * scale + shift);
        s_vtd[c][lane] = vt;
    }
    __syncthreads();

    const int ob = wid * 24;
    float accA[24], accB[24];
    #pragma unroll
    for (int oo = 0; oo < 24; ++oo) {
        accA[oo] = b21[ob + oo];
        accB[oo] = b22[ob + oo];
    }
    #pragma unroll 4
    for (int c = 0; c < CCH; ++c) {
        const float vl = s_vlr[c][lane];
        const float vt = s_vtd[c][lane];
        #pragma unroll
        for (int oo = 0; oo < 24; ++oo) {
            accA[oo] = fmaf(vl, w21[(ob + oo) * CCH + c], accA[oo]);
            accB[oo] = fmaf(vt, w22[(ob + oo) * CCH + c], accB[oo]);
        }
    }

    float* ob_ptr = h2 + (size_t)b * CCH * HWSZ + hw0 + lane;
    float sum = 0.f, sumsq = 0.f;
    #pragma unroll
    for (int oo = 0; oo < 24; ++oo) {
        const float r = gelu_f(accA[oo]) + gelu_f(accB[oo]);
        ob_ptr[(size_t)(ob + oo) * HWSZ] = r;
        sum += r;
        sumsq += r * r;
    }
    block_reduce_write(sum, sumsq, part, b * NBLK + blockIdx.x);
}

// ---------------- K5: gn2 + conv3 -> out -----------------------------------
__global__ __launch_bounds__(256) void k_out(
        const float* __restrict__ h2, const float* __restrict__ w3,
        const float* __restrict__ b3, const float* __restrict__ ms2,
        const float* __restrict__ gw, const float* __restrict__ gb,
        float* __restrict__ out) {
    __shared__ float sv[CCH][PIX];
    const int b = blockIdx.y;
    const int hw0 = blockIdx.x * PIX;
    const int wid = __builtin_amdgcn_readfirstlane(threadIdx.x >> 6);
    const int lane = threadIdx.x & 63;

    const float mu = ms2[2 * b + 0];
    const float inv = ms2[2 * b + 1];
    const float* hb = h2 + (size_t)b * CCH * HWSZ + hw0;
    #pragma unroll
    for (int i = 0; i < 24; ++i) {
        const int c = i * 4 + wid;
        const float scale = inv * gw[c];
        const float shift = gb[c] - mu * scale;
        sv[c][lane] = hb[(size_t)c * HWSZ + lane] * scale + shift;
    }
    __syncthreads();

    const int ob = wid * 24;
    float acc[24];
    #pragma unroll
    for (int oo = 0; oo < 24; ++oo) acc[oo] = b3[ob + oo];
    #pragma unroll 4
    for (int c = 0; c < CCH; ++c) {
        const float v = sv[c][lane];
        #pragma unroll
        for (int oo = 0; oo < 24; ++oo)
            acc[oo] = fmaf(v, w3[(ob + oo) * CCH + c], acc[oo]);
    }

    float* op = out + (size_t)b * CCH * HWSZ + hw0 + lane;
    #pragma unroll
    for (int oo = 0; oo < 24; ++oo)
        op[(size_t)(ob + oo) * HWSZ] = acc[oo];
}

extern "C" void kernel_launch(void* const* d_in, const int* in_sizes, int n_in,
                              void* d_out, int out_size, void* d_ws, size_t ws_size,
                              hipStream_t stream) {
    const float* x    = (const float*)d_in[0];
    const float* w1   = (const float*)d_in[1];
    const float* b1   = (const float*)d_in[2];
    const float* w21  = (const float*)d_in[3];
    const float* b21  = (const float*)d_in[4];
    const float* w22  = (const float*)d_in[5];
    const float* b22  = (const float*)d_in[6];
    const float* w3   = (const float*)d_in[7];
    const float* b3   = (const float*)d_in[8];
    const float* gn1w = (const float*)d_in[9];
    const float* gn1b = (const float*)d_in[10];
    const float* gn2w = (const float*)d_in[11];
    const float* gn2b = (const float*)d_in[12];

    float* out = (float*)d_out;
    float* ws  = (float*)d_ws;

    float* part = ws;                       // 32*196*2 = 12544 floats (reused)
    float* ms1  = ws + 12544;               // 64 floats
    float* ms2  = ws + 12608;               // 64 floats
    float* h2   = ws + 16384;               // 38535168 floats
    float* h1   = out;                      // stage conv1 output in d_out

    dim3 grid(NBLK, NB), blk(256);
    k_conv1<<<grid, blk, 0, stream>>>(x, w1, b1, h1, part);
    k_stats<<<dim3(NB), dim3(64), 0, stream>>>(part, ms1);
    k_mid<<<grid, blk, 0, stream>>>(h1, w21, b21, w22, b22, ms1, gn1w, gn1b, h2, part);
    k_stats<<<dim3(NB), dim3(64), 0, stream>>>(part, ms2);
    k_out<<<grid, blk, 0, stream>>>(h2, w3, b3, ms2, gn2w, gn2b, out);
}

// Round 3
// 366.579 us; speedup vs baseline: 4.5032x; 2.5559x over previous
//
#include <hip/hip_runtime.h>
#include <math.h>

#define CCH 96
#define HH 112
#define WW 112
#define HWSZ 12544      // 112*112
#define NB 32
#define PIX 64
#define NBLK 196        // 12544/64
#define EPSV 1e-5f
#define APITCH 120      // bf16 elems per A-row in LDS (240 B, 16B-aligned, 2-way banks)
#define TPITCH 72       // bf16 elems per transpose-row (144 B)
#define TPITCHF 68      // f32 elems per transpose-row in k_out (272 B)

typedef __attribute__((ext_vector_type(8))) short bf16x8;
typedef __attribute__((ext_vector_type(4))) float f32x4;

__device__ __forceinline__ unsigned short f2bf(float f) {
    union { float f; unsigned u; } v; v.f = f;
    unsigned r = v.u + 0x7fffu + ((v.u >> 16) & 1u);   // RTNE
    return (unsigned short)(r >> 16);
}
__device__ __forceinline__ float bf2f(unsigned short h) {
    union { unsigned u; float f; } v; v.u = ((unsigned)h) << 16;
    return v.f;
}
__device__ __forceinline__ float gelu_f(float x) {
    return 0.5f * x * (1.0f + erff(x * 0.70710678118654752f));
}

__device__ __forceinline__ void block_reduce_write(float sum, float sumsq,
                                                   float* part, int slot) {
    #pragma unroll
    for (int off = 32; off > 0; off >>= 1) {
        sum += __shfl_down(sum, off);
        sumsq += __shfl_down(sumsq, off);
    }
    __shared__ float ls[8];
    const int wid = threadIdx.x >> 6, lane = threadIdx.x & 63;
    if (lane == 0) { ls[wid] = sum; ls[4 + wid] = sumsq; }
    __syncthreads();
    if (threadIdx.x == 0) {
        part[slot * 2 + 0] = ls[0] + ls[1] + ls[2] + ls[3];
        part[slot * 2 + 1] = ls[4] + ls[5] + ls[6] + ls[7];
    }
}

// ---- weight prep: fp32 [O][C] -> bf16 fragment layout [m][n0][k0][lane][8] ----
// B[k][n] = w[n][k]; frag elem: B[k0*32 + (l>>4)*8 + j][n0*16 + (l&15)]
__global__ void k_prep(const float* __restrict__ w1, const float* __restrict__ w21,
                       const float* __restrict__ w22, const float* __restrict__ w3,
                       unsigned short* __restrict__ Bp) {
    const int t = blockIdx.x * 256 + threadIdx.x;   // 4*18*512 = 36864
    if (t >= 4 * 18 * 512) return;
    const int j  = t & 7;
    const int l  = (t >> 3) & 63;
    const int s  = t >> 9;                 // (m*6+n0)*3 + k0
    const int k0 = s % 3;
    const int n0 = (s / 3) % 6;
    const int m  = s / 18;
    const float* w = (m == 0) ? w1 : (m == 1) ? w21 : (m == 2) ? w22 : w3;
    const int n = n0 * 16 + (l & 15);
    const int k = k0 * 32 + (l >> 4) * 8 + j;
    Bp[t] = f2bf(w[n * CCH + k]);
}

// ---- K1: conv1 (x fp32 -> h1 bf16) + GN1 partials ----
__global__ __launch_bounds__(256) void k_conv1(
        const float* __restrict__ x, const unsigned short* __restrict__ Bp,
        const float* __restrict__ b1, unsigned short* __restrict__ h1,
        float* __restrict__ part) {
    __shared__ unsigned short smem[64 * APITCH];   // 15360 B; T (13824 B) reuses it
    unsigned short* Asd = smem;
    unsigned short* Tsd = smem;

    const int b = blockIdx.y;
    const int hw0 = blockIdx.x * PIX;
    const int wid = __builtin_amdgcn_readfirstlane(threadIdx.x >> 6);
    const int lane = threadIdx.x & 63;

    const float* xb = x + (size_t)b * CCH * HWSZ + hw0;
    #pragma unroll
    for (int i = 0; i < 24; i += 2) {
        const int c = wid * 24 + i;
        const unsigned lo = f2bf(xb[(size_t)c * HWSZ + lane]);
        const unsigned hi = f2bf(xb[(size_t)(c + 1) * HWSZ + lane]);
        *(unsigned*)&Asd[lane * APITCH + c] = lo | (hi << 16);
    }
    __syncthreads();

    bf16x8 a[3];
    const int arow = (wid * 16 + (lane & 15)) * APITCH;
    const int acol = (lane >> 4) * 8;
    #pragma unroll
    for (int k0 = 0; k0 < 3; ++k0)
        a[k0] = *(const bf16x8*)&Asd[arow + k0 * 32 + acol];
    __syncthreads();

    f32x4 acc[6];
    #pragma unroll
    for (int n0 = 0; n0 < 6; ++n0) {
        const float bias = b1[n0 * 16 + (lane & 15)];
        acc[n0] = (f32x4){bias, bias, bias, bias};
        #pragma unroll
        for (int k0 = 0; k0 < 3; ++k0) {
            const bf16x8 bf = *(const bf16x8*)(Bp + (n0 * 3 + k0) * 512 + lane * 8);
            acc[n0] = __builtin_amdgcn_mfma_f32_16x16x32_bf16(a[k0], bf, acc[n0], 0, 0, 0);
        }
    }

    float sum = 0.f, sumsq = 0.f;
    const int p0 = wid * 16 + (lane >> 4) * 4;
    #pragma unroll
    for (int n0 = 0; n0 < 6; ++n0) {
        const int o = n0 * 16 + (lane & 15);
        unsigned long long pk = 0;
        #pragma unroll
        for (int r = 0; r < 4; ++r) {
            const float v = acc[n0][r];
            sum += v; sumsq += v * v;
            pk |= (unsigned long long)f2bf(v) << (16 * r);
        }
        *(unsigned long long*)&Tsd[o * TPITCH + p0] = pk;
    }
    __syncthreads();

    unsigned short* hb = h1 + (size_t)b * CCH * HWSZ + hw0;
    #pragma unroll
    for (int it = 0; it < 6; ++it) {
        const int o = it * 16 + (threadIdx.x >> 4);
        const int p = (threadIdx.x & 15) * 4;
        *(unsigned long long*)&hb[(size_t)o * HWSZ + p] =
            *(const unsigned long long*)&Tsd[o * TPITCH + p];
    }
    block_reduce_write(sum, sumsq, part, b * NBLK + blockIdx.x);
}

// ---- stats: partials -> (mean, rsqrt(var+eps)) per sample ----
__global__ void k_stats(const float* __restrict__ part, float* __restrict__ ms) {
    const int b = blockIdx.x;
    const int t = threadIdx.x;
    float s = 0.f, q = 0.f;
    for (int i = t; i < NBLK; i += 64) {
        s += part[(b * NBLK + i) * 2 + 0];
        q += part[(b * NBLK + i) * 2 + 1];
    }
    #pragma unroll
    for (int off = 32; off > 0; off >>= 1) {
        s += __shfl_down(s, off);
        q += __shfl_down(q, off);
    }
    if (t == 0) {
        const float n = (float)CCH * (float)HWSZ;
        const float mu = s / n;
        const float var = q / n - mu * mu;
        ms[2 * b + 0] = mu;
        ms[2 * b + 1] = rsqrtf(var + EPSV);
    }
}

// ---- K3: gn1+gelu+shift -> 2 GEMMs -> gelu+add -> h2 bf16 + GN2 partials ----
__global__ __launch_bounds__(256) void k_mid(
        const unsigned short* __restrict__ h1,
        const unsigned short* __restrict__ BpA, const unsigned short* __restrict__ BpB,
        const float* __restrict__ b21, const float* __restrict__ b22,
        const float* __restrict__ ms1,
        const float* __restrict__ gw, const float* __restrict__ gb,
        unsigned short* __restrict__ h2, float* __restrict__ part) {
    __shared__ unsigned short smem[2 * 64 * APITCH];   // 30720 B
    unsigned short* Alr = smem;
    unsigned short* Atd = smem + 64 * APITCH;
    unsigned short* Tsd = smem;                         // reuses Alr region

    const int b = blockIdx.y;
    const int hw0 = blockIdx.x * PIX;
    const int wid = __builtin_amdgcn_readfirstlane(threadIdx.x >> 6);
    const int lane = threadIdx.x & 63;

    const float mu = ms1[2 * b + 0];
    const float inv = ms1[2 * b + 1];
    const unsigned short* hbase = h1 + (size_t)b * CCH * HWSZ;
    const int hw = hw0 + lane;
    const int h = hw / WW, w = hw % WW;

    #pragma unroll
    for (int i = 0; i < 24; i += 2) {
        const int c = wid * 24 + i;
        const int d = (c < 32) ? 1 : (c < 64) ? 0 : -1;
        unsigned lr = 0, td = 0;
        #pragma unroll
        for (int q = 0; q < 2; ++q) {
            const int cc = c + q;
            const float scale = inv * gw[cc];
            const float shift = gb[cc] - mu * scale;
            const size_t cb = (size_t)cc * HWSZ;
            float vl = 0.f, vt = 0.f;
            const int wp = w + d;
            if (wp >= 0 && wp < WW)
                vl = gelu_f(bf2f(hbase[cb + hw + d]) * scale + shift);
            const int hp = h + d;
            if (hp >= 0 && hp < HH)
                vt = gelu_f(bf2f(hbase[cb + hw + d * WW]) * scale + shift);
            lr |= (unsigned)f2bf(vl) << (16 * q);
            td |= (unsigned)f2bf(vt) << (16 * q);
        }
        *(unsigned*)&Alr[lane * APITCH + c] = lr;
        *(unsigned*)&Atd[lane * APITCH + c] = td;
    }
    __syncthreads();

    bf16x8 alr[3], atd[3];
    const int arow = (wid * 16 + (lane & 15)) * APITCH;
    const int acol = (lane >> 4) * 8;
    #pragma unroll
    for (int k0 = 0; k0 < 3; ++k0) {
        alr[k0] = *(const bf16x8*)&Alr[arow + k0 * 32 + acol];
        atd[k0] = *(const bf16x8*)&Atd[arow + k0 * 32 + acol];
    }
    __syncthreads();

    f32x4 accA[6], accB[6];
    #pragma unroll
    for (int n0 = 0; n0 < 6; ++n0) {
        const float biasA = b21[n0 * 16 + (lane & 15)];
        const float biasB = b22[n0 * 16 + (lane & 15)];
        accA[n0] = (f32x4){biasA, biasA, biasA, biasA};
        accB[n0] = (f32x4){biasB, biasB, biasB, biasB};
        #pragma unroll
        for (int k0 = 0; k0 < 3; ++k0) {
            const bf16x8 bA = *(const bf16x8*)(BpA + (n0 * 3 + k0) * 512 + lane * 8);
            const bf16x8 bB = *(const bf16x8*)(BpB + (n0 * 3 + k0) * 512 + lane * 8);
            accA[n0] = __builtin_amdgcn_mfma_f32_16x16x32_bf16(alr[k0], bA, accA[n0], 0, 0, 0);
            accB[n0] = __builtin_amdgcn_mfma_f32_16x16x32_bf16(atd[k0], bB, accB[n0], 0, 0, 0);
        }
    }

    float sum = 0.f, sumsq = 0.f;
    const int p0 = wid * 16 + (lane >> 4) * 4;
    #pragma unroll
    for (int n0 = 0; n0 < 6; ++n0) {
        const int o = n0 * 16 + (lane & 15);
        unsigned long long pk = 0;
        #pragma unroll
        for (int r = 0; r < 4; ++r) {
            const float v = gelu_f(accA[n0][r]) + gelu_f(accB[n0][r]);
            sum += v; sumsq += v * v;
            pk |= (unsigned long long)f2bf(v) << (16 * r);
        }
        *(unsigned long long*)&Tsd[o * TPITCH + p0] = pk;
    }
    __syncthreads();

    unsigned short* ob = h2 + (size_t)b * CCH * HWSZ + hw0;
    #pragma unroll
    for (int it = 0; it < 6; ++it) {
        const int o = it * 16 + (threadIdx.x >> 4);
        const int p = (threadIdx.x & 15) * 4;
        *(unsigned long long*)&ob[(size_t)o * HWSZ + p] =
            *(const unsigned long long*)&Tsd[o * TPITCH + p];
    }
    block_reduce_write(sum, sumsq, part, b * NBLK + blockIdx.x);
}

// ---- K5: gn2 affine -> conv3 -> out fp32 ----
__global__ __launch_bounds__(256) void k_out(
        const unsigned short* __restrict__ h2, const unsigned short* __restrict__ Bp,
        const float* __restrict__ b3, const float* __restrict__ ms2,
        const float* __restrict__ gw, const float* __restrict__ gb,
        float* __restrict__ out) {
    __shared__ float smemf[96 * TPITCHF];     // 26112 B; Asd (15360 B) overlaps
    unsigned short* Asd = (unsigned short*)smemf;
    float* Tf = smemf;

    const int b = blockIdx.y;
    const int hw0 = blockIdx.x * PIX;
    const int wid = __builtin_amdgcn_readfirstlane(threadIdx.x >> 6);
    const int lane = threadIdx.x & 63;

    const float mu = ms2[2 * b + 0];
    const float inv = ms2[2 * b + 1];
    const unsigned short* hb = h2 + (size_t)b * CCH * HWSZ + hw0;
    #pragma unroll
    for (int i = 0; i < 24; i += 2) {
        const int c = wid * 24 + i;
        unsigned pk = 0;
        #pragma unroll
        for (int q = 0; q < 2; ++q) {
            const int cc = c + q;
            const float scale = inv * gw[cc];
            const float shift = gb[cc] - mu * scale;
            const float v = bf2f(hb[(size_t)cc * HWSZ + lane]) * scale + shift;
            pk |= (unsigned)f2bf(v) << (16 * q);
        }
        *(unsigned*)&Asd[lane * APITCH + c] = pk;
    }
    __syncthreads();

    bf16x8 a[3];
    const int arow = (wid * 16 + (lane & 15)) * APITCH;
    const int acol = (lane >> 4) * 8;
    #pragma unroll
    for (int k0 = 0; k0 < 3; ++k0)
        a[k0] = *(const bf16x8*)&Asd[arow + k0 * 32 + acol];
    __syncthreads();

    f32x4 acc[6];
    #pragma unroll
    for (int n0 = 0; n0 < 6; ++n0) {
        const float bias = b3[n0 * 16 + (lane & 15)];
        acc[n0] = (f32x4){bias, bias, bias, bias};
        #pragma unroll
        for (int k0 = 0; k0 < 3; ++k0) {
            const bf16x8 bf = *(const bf16x8*)(Bp + (n0 * 3 + k0) * 512 + lane * 8);
            acc[n0] = __builtin_amdgcn_mfma_f32_16x16x32_bf16(a[k0], bf, acc[n0], 0, 0, 0);
        }
    }

    const int p0 = wid * 16 + (lane >> 4) * 4;
    #pragma unroll
    for (int n0 = 0; n0 < 6; ++n0) {
        const int o = n0 * 16 + (lane & 15);
        *(f32x4*)&Tf[o * TPITCHF + p0] = acc[n0];
    }
    __syncthreads();

    float* op = out + (size_t)b * CCH * HWSZ + hw0;
    #pragma unroll
    for (int it = 0; it < 12; ++it) {
        const int o = it * 8 + (threadIdx.x >> 5);
        const int p = (threadIdx.x & 31) * 2;
        *(float2*)&op[(size_t)o * HWSZ + p] = *(const float2*)&Tf[o * TPITCHF + p];
    }
}

extern "C" void kernel_launch(void* const* d_in, const int* in_sizes, int n_in,
                              void* d_out, int out_size, void* d_ws, size_t ws_size,
                              hipStream_t stream) {
    const float* x    = (const float*)d_in[0];
    const float* w1   = (const float*)d_in[1];
    const float* b1   = (const float*)d_in[2];
    const float* w21  = (const float*)d_in[3];
    const float* b21  = (const float*)d_in[4];
    const float* w22  = (const float*)d_in[5];
    const float* b22  = (const float*)d_in[6];
    const float* w3   = (const float*)d_in[7];
    const float* b3   = (const float*)d_in[8];
    const float* gn1w = (const float*)d_in[9];
    const float* gn1b = (const float*)d_in[10];
    const float* gn2w = (const float*)d_in[11];
    const float* gn2b = (const float*)d_in[12];

    char* base = (char*)d_ws;
    unsigned short* Bp   = (unsigned short*)base;            // 36864 bf16 = 73728 B
    float*          part = (float*)(base + 73728);           // 12544 f = 50176 B
    float*          ms1  = (float*)(base + 123904);          // 64 f
    float*          ms2  = (float*)(base + 124160);          // 64 f
    unsigned short* h2   = (unsigned short*)(base + 131072); // 77 MB bf16
    unsigned short* h1   = (unsigned short*)d_out;           // stage h1 bf16 in d_out

    dim3 grid(NBLK, NB), blk(256);
    k_prep<<<dim3(144), blk, 0, stream>>>(w1, w21, w22, w3, Bp);
    k_conv1<<<grid, blk, 0, stream>>>(x, Bp, b1, h1, part);
    k_stats<<<dim3(NB), dim3(64), 0, stream>>>(part, ms1);
    k_mid<<<grid, blk, 0, stream>>>(h1, Bp + 18 * 512, Bp + 36 * 512,
                                    b21, b22, ms1, gn1w, gn1b, h2, part);
    k_stats<<<dim3(NB), dim3(64), 0, stream>>>(part, ms2);
    k_out<<<grid, blk, 0, stream>>>(h2, Bp + 54 * 512, b3, ms2, gn2w, gn2b, (float*)d_out);
}

// Round 5
// 240.089 us; speedup vs baseline: 6.8757x; 1.5268x over previous
//
#include <hip/hip_runtime.h>
#include <math.h>

#define CCH 96
#define HH 112
#define WW 112
#define HWSZ 12544      // 112*112
#define NB 32
#define PIX 64
#define NBLK 196        // 12544/64
#define EPSV 1e-5f
#define APITCH 120      // bf16 elems per A-row in LDS
#define TPITCH 72       // bf16 elems per transpose-row
#define TPITCHF 68      // f32 elems per transpose-row in k_out

typedef __attribute__((ext_vector_type(8))) short bf16x8;
typedef __attribute__((ext_vector_type(4))) float f32x4;

__device__ __forceinline__ unsigned short f2bf(float f) {
    union { float f; unsigned u; } v; v.f = f;
    unsigned r = v.u + 0x7fffu + ((v.u >> 16) & 1u);   // RTNE
    return (unsigned short)(r >> 16);
}
__device__ __forceinline__ float bf2f(unsigned short h) {
    union { unsigned u; float f; } v; v.u = ((unsigned)h) << 16;
    return v.f;
}
// tanh-form GELU via hw exp2/rcp: gelu(x) = x - x/(1 + e^{2y}),
// y = 0.7978845608*(x + 0.044715 x^3).  K = 2*0.7978845608*log2(e).
// |err| vs exact erf-GELU < ~1.5e-3 (far under bf16 noise already present).
__device__ __forceinline__ float gelu_f(float x) {
    const float K = 2.3022082f;
    float u = x * x;
    float p = x * fmaf(0.044715f, u, 1.0f);
    float e = __builtin_amdgcn_exp2f(p * K);
    float r = __builtin_amdgcn_rcpf(e + 1.0f);
    return x - x * r;
}

__device__ __forceinline__ void block_reduce_write(float sum, float sumsq,
                                                   float* part, int slot) {
    #pragma unroll
    for (int off = 32; off > 0; off >>= 1) {
        sum += __shfl_down(sum, off);
        sumsq += __shfl_down(sumsq, off);
    }
    __shared__ float ls[8];
    const int wid = threadIdx.x >> 6, lane = threadIdx.x & 63;
    if (lane == 0) { ls[wid] = sum; ls[4 + wid] = sumsq; }
    __syncthreads();
    if (threadIdx.x == 0) {
        part[slot * 2 + 0] = ls[0] + ls[1] + ls[2] + ls[3];
        part[slot * 2 + 1] = ls[4] + ls[5] + ls[6] + ls[7];
    }
}

// ---- weight prep: fp32 [O][C] -> bf16 fragment layout [m][n0][k0][lane][8] ----
__global__ void k_prep(const float* __restrict__ w1, const float* __restrict__ w21,
                       const float* __restrict__ w22, const float* __restrict__ w3,
                       unsigned short* __restrict__ Bp) {
    const int t = blockIdx.x * 256 + threadIdx.x;   // 4*18*512 = 36864
    if (t >= 4 * 18 * 512) return;
    const int j  = t & 7;
    const int l  = (t >> 3) & 63;
    const int s  = t >> 9;
    const int k0 = s % 3;
    const int n0 = (s / 3) % 6;
    const int m  = s / 18;
    const float* w = (m == 0) ? w1 : (m == 1) ? w21 : (m == 2) ? w22 : w3;
    const int n = n0 * 16 + (l & 15);
    const int k = k0 * 32 + (l >> 4) * 8 + j;
    Bp[t] = f2bf(w[n * CCH + k]);
}

// ---- K1: conv1 (x fp32 -> h1 bf16) + GN1 partials ----
__global__ __launch_bounds__(256) void k_conv1(
        const float* __restrict__ x, const unsigned short* __restrict__ Bp,
        const float* __restrict__ b1, unsigned short* __restrict__ h1,
        float* __restrict__ part) {
    __shared__ unsigned short smem[64 * APITCH];
    unsigned short* Asd = smem;
    unsigned short* Tsd = smem;

    const int b = blockIdx.y;
    const int hw0 = blockIdx.x * PIX;
    const int wid = __builtin_amdgcn_readfirstlane(threadIdx.x >> 6);
    const int lane = threadIdx.x & 63;

    const float* xb = x + (size_t)b * CCH * HWSZ + hw0;
    #pragma unroll
    for (int i = 0; i < 24; i += 2) {
        const int c = wid * 24 + i;
        const unsigned lo = f2bf(xb[(size_t)c * HWSZ + lane]);
        const unsigned hi = f2bf(xb[(size_t)(c + 1) * HWSZ + lane]);
        *(unsigned*)&Asd[lane * APITCH + c] = lo | (hi << 16);
    }
    __syncthreads();

    bf16x8 a[3];
    const int arow = (wid * 16 + (lane & 15)) * APITCH;
    const int acol = (lane >> 4) * 8;
    #pragma unroll
    for (int k0 = 0; k0 < 3; ++k0)
        a[k0] = *(const bf16x8*)&Asd[arow + k0 * 32 + acol];
    __syncthreads();

    f32x4 acc[6];
    #pragma unroll
    for (int n0 = 0; n0 < 6; ++n0) {
        const float bias = b1[n0 * 16 + (lane & 15)];
        acc[n0] = (f32x4){bias, bias, bias, bias};
        #pragma unroll
        for (int k0 = 0; k0 < 3; ++k0) {
            const bf16x8 bf = *(const bf16x8*)(Bp + (n0 * 3 + k0) * 512 + lane * 8);
            acc[n0] = __builtin_amdgcn_mfma_f32_16x16x32_bf16(a[k0], bf, acc[n0], 0, 0, 0);
        }
    }

    float sum = 0.f, sumsq = 0.f;
    const int p0 = wid * 16 + (lane >> 4) * 4;
    #pragma unroll
    for (int n0 = 0; n0 < 6; ++n0) {
        const int o = n0 * 16 + (lane & 15);
        unsigned long long pk = 0;
        #pragma unroll
        for (int r = 0; r < 4; ++r) {
            const float v = acc[n0][r];
            sum += v; sumsq += v * v;
            pk |= (unsigned long long)f2bf(v) << (16 * r);
        }
        *(unsigned long long*)&Tsd[o * TPITCH + p0] = pk;
    }
    __syncthreads();

    unsigned short* hb = h1 + (size_t)b * CCH * HWSZ + hw0;
    #pragma unroll
    for (int it = 0; it < 6; ++it) {
        const int o = it * 16 + (threadIdx.x >> 4);
        const int p = (threadIdx.x & 15) * 4;
        *(unsigned long long*)&hb[(size_t)o * HWSZ + p] =
            *(const unsigned long long*)&Tsd[o * TPITCH + p];
    }
    block_reduce_write(sum, sumsq, part, b * NBLK + blockIdx.x);
}

// ---- stats: partials -> (mean, rsqrt(var+eps)) per sample ----
__global__ void k_stats(const float* __restrict__ part, float* __restrict__ ms) {
    const int b = blockIdx.x;
    const int t = threadIdx.x;
    float s = 0.f, q = 0.f;
    for (int i = t; i < NBLK; i += 64) {
        s += part[(b * NBLK + i) * 2 + 0];
        q += part[(b * NBLK + i) * 2 + 1];
    }
    #pragma unroll
    for (int off = 32; off > 0; off >>= 1) {
        s += __shfl_down(s, off);
        q += __shfl_down(q, off);
    }
    if (t == 0) {
        const float n = (float)CCH * (float)HWSZ;
        const float mu = s / n;
        const float var = q / n - mu * mu;
        ms[2 * b + 0] = mu;
        ms[2 * b + 1] = rsqrtf(var + EPSV);
    }
}

// ---- K3: gn1+gelu+shift -> 2 GEMMs -> gelu+add -> h2 bf16 + GN2 partials ----
__global__ __launch_bounds__(256) void k_mid(
        const unsigned short* __restrict__ h1,
        const unsigned short* __restrict__ BpA, const unsigned short* __restrict__ BpB,
        const float* __restrict__ b21, const float* __restrict__ b22,
        const float* __restrict__ ms1,
        const float* __restrict__ gw, const float* __restrict__ gb,
        unsigned short* __restrict__ h2, float* __restrict__ part) {
    __shared__ unsigned short smem[2 * 64 * APITCH];
    unsigned short* Alr = smem;
    unsigned short* Atd = smem + 64 * APITCH;
    unsigned short* Tsd = smem;

    const int b = blockIdx.y;
    const int hw0 = blockIdx.x * PIX;
    const int wid = __builtin_amdgcn_readfirstlane(threadIdx.x >> 6);
    const int lane = threadIdx.x & 63;

    const float mu = ms1[2 * b + 0];
    const float inv = ms1[2 * b + 1];
    const unsigned short* hbase = h1 + (size_t)b * CCH * HWSZ;
    const int hw = hw0 + lane;
    const int h = hw / WW, w = hw % WW;

    #pragma unroll
    for (int i = 0; i < 24; i += 2) {
        const int c = wid * 24 + i;
        const int d = (c < 32) ? 1 : (c < 64) ? 0 : -1;
        unsigned lr = 0, td = 0;
        #pragma unroll
        for (int q = 0; q < 2; ++q) {
            const int cc = c + q;
            const float scale = inv * gw[cc];
            const float shift = gb[cc] - mu * scale;
            const size_t cb = (size_t)cc * HWSZ;
            float vl = 0.f, vt = 0.f;
            const int wp = w + d;
            if (wp >= 0 && wp < WW)
                vl = gelu_f(bf2f(hbase[cb + hw + d]) * scale + shift);
            const int hp = h + d;
            if (hp >= 0 && hp < HH)
                vt = gelu_f(bf2f(hbase[cb + hw + d * WW]) * scale + shift);
            lr |= (unsigned)f2bf(vl) << (16 * q);
            td |= (unsigned)f2bf(vt) << (16 * q);
        }
        *(unsigned*)&Alr[lane * APITCH + c] = lr;
        *(unsigned*)&Atd[lane * APITCH + c] = td;
    }
    __syncthreads();

    bf16x8 alr[3], atd[3];
    const int arow = (wid * 16 + (lane & 15)) * APITCH;
    const int acol = (lane >> 4) * 8;
    #pragma unroll
    for (int k0 = 0; k0 < 3; ++k0) {
        alr[k0] = *(const bf16x8*)&Alr[arow + k0 * 32 + acol];
        atd[k0] = *(const bf16x8*)&Atd[arow + k0 * 32 + acol];
    }
    __syncthreads();

    f32x4 accA[6], accB[6];
    #pragma unroll
    for (int n0 = 0; n0 < 6; ++n0) {
        const float biasA = b21[n0 * 16 + (lane & 15)];
        const float biasB = b22[n0 * 16 + (lane & 15)];
        accA[n0] = (f32x4){biasA, biasA, biasA, biasA};
        accB[n0] = (f32x4){biasB, biasB, biasB, biasB};
        #pragma unroll
        for (int k0 = 0; k0 < 3; ++k0) {
            const bf16x8 bA = *(const bf16x8*)(BpA + (n0 * 3 + k0) * 512 + lane * 8);
            const bf16x8 bB = *(const bf16x8*)(BpB + (n0 * 3 + k0) * 512 + lane * 8);
            accA[n0] = __builtin_amdgcn_mfma_f32_16x16x32_bf16(alr[k0], bA, accA[n0], 0, 0, 0);
            accB[n0] = __builtin_amdgcn_mfma_f32_16x16x32_bf16(atd[k0], bB, accB[n0], 0, 0, 0);
        }
    }

    float sum = 0.f, sumsq = 0.f;
    const int p0 = wid * 16 + (lane >> 4) * 4;
    #pragma unroll
    for (int n0 = 0; n0 < 6; ++n0) {
        const int o = n0 * 16 + (lane & 15);
        unsigned long long pk = 0;
        #pragma unroll
        for (int r = 0; r < 4; ++r) {
            const float v = gelu_f(accA[n0][r]) + gelu_f(accB[n0][r]);
            sum += v; sumsq += v * v;
            pk |= (unsigned long long)f2bf(v) << (16 * r);
        }
        *(unsigned long long*)&Tsd[o * TPITCH + p0] = pk;
    }
    __syncthreads();

    unsigned short* ob = h2 + (size_t)b * CCH * HWSZ + hw0;
    #pragma unroll
    for (int it = 0; it < 6; ++it) {
        const int o = it * 16 + (threadIdx.x >> 4);
        const int p = (threadIdx.x & 15) * 4;
        *(unsigned long long*)&ob[(size_t)o * HWSZ + p] =
            *(const unsigned long long*)&Tsd[o * TPITCH + p];
    }
    block_reduce_write(sum, sumsq, part, b * NBLK + blockIdx.x);
}

// ---- K5: gn2 affine -> conv3 -> out fp32 ----
__global__ __launch_bounds__(256) void k_out(
        const unsigned short* __restrict__ h2, const unsigned short* __restrict__ Bp,
        const float* __restrict__ b3, const float* __restrict__ ms2,
        const float* __restrict__ gw, const float* __restrict__ gb,
        float* __restrict__ out) {
    __shared__ float smemf[96 * TPITCHF];
    unsigned short* Asd = (unsigned short*)smemf;
    float* Tf = smemf;

    const int b = blockIdx.y;
    const int hw0 = blockIdx.x * PIX;
    const int wid = __builtin_amdgcn_readfirstlane(threadIdx.x >> 6);
    const int lane = threadIdx.x & 63;

    const float mu = ms2[2 * b + 0];
    const float inv = ms2[2 * b + 1];
    const unsigned short* hb = h2 + (size_t)b * CCH * HWSZ + hw0;
    #pragma unroll
    for (int i = 0; i < 24; i += 2) {
        const int c = wid * 24 + i;
        unsigned pk = 0;
        #pragma unroll
        for (int q = 0; q < 2; ++q) {
            const int cc = c + q;
            const float scale = inv * gw[cc];
            const float shift = gb[cc] - mu * scale;
            const float v = bf2f(hb[(size_t)cc * HWSZ + lane]) * scale + shift;
            pk |= (unsigned)f2bf(v) << (16 * q);
        }
        *(unsigned*)&Asd[lane * APITCH + c] = pk;
    }
    __syncthreads();

    bf16x8 a[3];
    const int arow = (wid * 16 + (lane & 15)) * APITCH;
    const int acol = (lane >> 4) * 8;
    #pragma unroll
    for (int k0 = 0; k0 < 3; ++k0)
        a[k0] = *(const bf16x8*)&Asd[arow + k0 * 32 + acol];
    __syncthreads();

    f32x4 acc[6];
    #pragma unroll
    for (int n0 = 0; n0 < 6; ++n0) {
        const float bias = b3[n0 * 16 + (lane & 15)];
        acc[n0] = (f32x4){bias, bias, bias, bias};
        #pragma unroll
        for (int k0 = 0; k0 < 3; ++k0) {
            const bf16x8 bf = *(const bf16x8*)(Bp + (n0 * 3 + k0) * 512 + lane * 8);
            acc[n0] = __builtin_amdgcn_mfma_f32_16x16x32_bf16(a[k0], bf, acc[n0], 0, 0, 0);
        }
    }

    const int p0 = wid * 16 + (lane >> 4) * 4;
    #pragma unroll
    for (int n0 = 0; n0 < 6; ++n0) {
        const int o = n0 * 16 + (lane & 15);
        *(f32x4*)&Tf[o * TPITCHF + p0] = acc[n0];
    }
    __syncthreads();

    float* op = out + (size_t)b * CCH * HWSZ + hw0;
    #pragma unroll
    for (int it = 0; it < 12; ++it) {
        const int o = it * 8 + (threadIdx.x >> 5);
        const int p = (threadIdx.x & 31) * 2;
        *(float2*)&op[(size_t)o * HWSZ + p] = *(const float2*)&Tf[o * TPITCHF + p];
    }
}

extern "C" void kernel_launch(void* const* d_in, const int* in_sizes, int n_in,
                              void* d_out, int out_size, void* d_ws, size_t ws_size,
                              hipStream_t stream) {
    const float* x    = (const float*)d_in[0];
    const float* w1   = (const float*)d_in[1];
    const float* b1   = (const float*)d_in[2];
    const float* w21  = (const float*)d_in[3];
    const float* b21  = (const float*)d_in[4];
    const float* w22  = (const float*)d_in[5];
    const float* b22  = (const float*)d_in[6];
    const float* w3   = (const float*)d_in[7];
    const float* b3   = (const float*)d_in[8];
    const float* gn1w = (const float*)d_in[9];
    const float* gn1b = (const float*)d_in[10];
    const float* gn2w = (const float*)d_in[11];
    const float* gn2b = (const float*)d_in[12];

    char* base = (char*)d_ws;
    unsigned short* Bp   = (unsigned short*)base;            // 36864 bf16 = 73728 B
    float*          part = (float*)(base + 73728);           // 12544 f = 50176 B
    float*          ms1  = (float*)(base + 123904);          // 64 f
    float*          ms2  = (float*)(base + 124160);          // 64 f
    unsigned short* h2   = (unsigned short*)(base + 131072); // 77 MB bf16
    unsigned short* h1   = (unsigned short*)d_out;           // stage h1 bf16 in d_out

    dim3 grid(NBLK, NB), blk(256);
    k_prep<<<dim3(144), blk, 0, stream>>>(w1, w21, w22, w3, Bp);
    k_conv1<<<grid, blk, 0, stream>>>(x, Bp, b1, h1, part);
    k_stats<<<dim3(NB), dim3(64), 0, stream>>>(part, ms1);
    k_mid<<<grid, blk, 0, stream>>>(h1, Bp + 18 * 512, Bp + 36 * 512,
                                    b21, b22, ms1, gn1w, gn1b, h2, part);
    k_stats<<<dim3(NB), dim3(64), 0, stream>>>(part, ms2);
    k_out<<<grid, blk, 0, stream>>>(h2, Bp + 54 * 512, b3, ms2, gn2w, gn2b, (float*)d_out);
}

// Round 6
// 219.945 us; speedup vs baseline: 7.5054x; 1.0916x over previous
//
#include <hip/hip_runtime.h>
#include <math.h>

#define CCH 96
#define HH 112
#define WW 112
#define HWSZ 12544      // 112*112
#define NB 32
#define PIX 64
#define NBLK 196        // 12544/64
#define EPSV 1e-5f
#define APITCH 120      // bf16 elems per A-row in LDS
#define TPITCH 72       // bf16 elems per transpose-row
#define TPITCHF 68      // f32 elems per transpose-row in k_out

typedef __attribute__((ext_vector_type(8))) short bf16x8;
typedef __attribute__((ext_vector_type(4))) float f32x4;
typedef __attribute__((ext_vector_type(8))) unsigned short u16x8;

__device__ __forceinline__ float bf2f(unsigned short h) {
    union { unsigned u; float f; } v; v.u = ((unsigned)h) << 16;
    return v.f;
}
// single-instruction packed f32->bf16 (RTNE), gfx950
__device__ __forceinline__ unsigned cvt_pk_bf16(float lo, float hi) {
    unsigned r;
    asm("v_cvt_pk_bf16_f32 %0, %1, %2" : "=v"(r) : "v"(lo), "v"(hi));
    return r;
}
// tanh-form GELU via hw exp2/rcp: gelu(x) = x - x/(1 + e^{2y}),
// y = 0.7978845608*(x + 0.044715 x^3).  K = 2*0.7978845608*log2(e).
__device__ __forceinline__ float gelu_f(float x) {
    const float K = 2.3022082f;
    float u = x * x;
    float p = x * fmaf(0.044715f, u, 1.0f);
    float e = __builtin_amdgcn_exp2f(p * K);
    float r = __builtin_amdgcn_rcpf(e + 1.0f);
    return x - x * r;
}

__device__ __forceinline__ void block_reduce_write(float sum, float sumsq,
                                                   float* part, int slot) {
    #pragma unroll
    for (int off = 32; off > 0; off >>= 1) {
        sum += __shfl_down(sum, off);
        sumsq += __shfl_down(sumsq, off);
    }
    __shared__ float ls[8];
    const int wid = threadIdx.x >> 6, lane = threadIdx.x & 63;
    if (lane == 0) { ls[wid] = sum; ls[4 + wid] = sumsq; }
    __syncthreads();
    if (threadIdx.x == 0) {
        part[slot * 2 + 0] = ls[0] + ls[1] + ls[2] + ls[3];
        part[slot * 2 + 1] = ls[4] + ls[5] + ls[6] + ls[7];
    }
}

// ---- weight prep: fp32 [O][C] -> bf16 fragment layout [m][n0][k0][lane][8] ----
__global__ void k_prep(const float* __restrict__ w1, const float* __restrict__ w21,
                       const float* __restrict__ w22, const float* __restrict__ w3,
                       unsigned short* __restrict__ Bp) {
    const int t = blockIdx.x * 256 + threadIdx.x;   // 4*18*512 = 36864
    if (t >= 4 * 18 * 512) return;
    const int j  = t & 7;
    const int l  = (t >> 3) & 63;
    const int s  = t >> 9;
    const int k0 = s % 3;
    const int n0 = (s / 3) % 6;
    const int m  = s / 18;
    const float* w = (m == 0) ? w1 : (m == 1) ? w21 : (m == 2) ? w22 : w3;
    const int n = n0 * 16 + (l & 15);
    const int k = k0 * 32 + (l >> 4) * 8 + j;
    union { float f; unsigned u; } v; v.f = w[n * CCH + k];
    unsigned r = v.u + 0x7fffu + ((v.u >> 16) & 1u);
    Bp[t] = (unsigned short)(r >> 16);
}

// ---- K1: conv1 (x fp32 -> h1 bf16) + GN1 partials ----
__global__ __launch_bounds__(256) void k_conv1(
        const float* __restrict__ x, const unsigned short* __restrict__ Bp,
        const float* __restrict__ b1, unsigned short* __restrict__ h1,
        float* __restrict__ part) {
    __shared__ unsigned short smem[64 * APITCH];
    unsigned short* Asd = smem;
    unsigned short* Tsd = smem;

    const int b = blockIdx.y;
    const int hw0 = blockIdx.x * PIX;
    const int wid = __builtin_amdgcn_readfirstlane(threadIdx.x >> 6);
    const int lane = threadIdx.x & 63;

    const float* xb = x + (size_t)b * CCH * HWSZ + hw0;
    #pragma unroll
    for (int i = 0; i < 24; i += 2) {
        const int c = wid * 24 + i;
        *(unsigned*)&Asd[lane * APITCH + c] =
            cvt_pk_bf16(xb[(size_t)c * HWSZ + lane], xb[(size_t)(c + 1) * HWSZ + lane]);
    }
    __syncthreads();

    bf16x8 a[3];
    const int arow = (wid * 16 + (lane & 15)) * APITCH;
    const int acol = (lane >> 4) * 8;
    #pragma unroll
    for (int k0 = 0; k0 < 3; ++k0)
        a[k0] = *(const bf16x8*)&Asd[arow + k0 * 32 + acol];
    __syncthreads();

    f32x4 acc[6];
    #pragma unroll
    for (int n0 = 0; n0 < 6; ++n0) {
        const float bias = b1[n0 * 16 + (lane & 15)];
        acc[n0] = (f32x4){bias, bias, bias, bias};
        #pragma unroll
        for (int k0 = 0; k0 < 3; ++k0) {
            const bf16x8 bf = *(const bf16x8*)(Bp + (n0 * 3 + k0) * 512 + lane * 8);
            acc[n0] = __builtin_amdgcn_mfma_f32_16x16x32_bf16(a[k0], bf, acc[n0], 0, 0, 0);
        }
    }

    float sum = 0.f, sumsq = 0.f;
    const int p0 = wid * 16 + (lane >> 4) * 4;
    #pragma unroll
    for (int n0 = 0; n0 < 6; ++n0) {
        const int o = n0 * 16 + (lane & 15);
        #pragma unroll
        for (int r = 0; r < 4; ++r) {
            const float v = acc[n0][r];
            sum += v; sumsq += v * v;
        }
        const unsigned lo = cvt_pk_bf16(acc[n0][0], acc[n0][1]);
        const unsigned hi = cvt_pk_bf16(acc[n0][2], acc[n0][3]);
        *(uint2*)&Tsd[o * TPITCH + p0] = make_uint2(lo, hi);
    }
    __syncthreads();

    unsigned short* hb = h1 + (size_t)b * CCH * HWSZ + hw0;
    #pragma unroll
    for (int it = 0; it < 6; ++it) {
        const int o = it * 16 + (threadIdx.x >> 4);
        const int p = (threadIdx.x & 15) * 4;
        *(unsigned long long*)&hb[(size_t)o * HWSZ + p] =
            *(const unsigned long long*)&Tsd[o * TPITCH + p];
    }
    block_reduce_write(sum, sumsq, part, b * NBLK + blockIdx.x);
}

// ---- stats: partials -> (mean, rsqrt(var+eps)) per sample ----
__global__ void k_stats(const float* __restrict__ part, float* __restrict__ ms) {
    const int b = blockIdx.x;
    const int t = threadIdx.x;
    float s = 0.f, q = 0.f;
    for (int i = t; i < NBLK; i += 64) {
        s += part[(b * NBLK + i) * 2 + 0];
        q += part[(b * NBLK + i) * 2 + 1];
    }
    #pragma unroll
    for (int off = 32; off > 0; off >>= 1) {
        s += __shfl_down(s, off);
        q += __shfl_down(q, off);
    }
    if (t == 0) {
        const float n = (float)CCH * (float)HWSZ;
        const float mu = s / n;
        const float var = q / n - mu * mu;
        ms[2 * b + 0] = mu;
        ms[2 * b + 1] = rsqrtf(var + EPSV);
    }
}

// ---- K2.5: g = gelu(gn1(h1)) elementwise, IN-PLACE over h1 ----
__global__ __launch_bounds__(256) void k_gact(
        unsigned short* __restrict__ g, const float* __restrict__ ms,
        const float* __restrict__ gw, const float* __restrict__ gb) {
    const int NVEC = NB * CCH * (HWSZ / 8);   // 4816896
    for (int v = blockIdx.x * 256 + threadIdx.x; v < NVEC; v += 2048 * 256) {
        const int bc = v / (HWSZ / 8);
        const int b = bc / CCH, c = bc % CCH;
        const float scale = ms[2 * b + 1] * gw[c];
        const float shift = gb[c] - ms[2 * b] * scale;
        const u16x8 gv = *(const u16x8*)&g[(size_t)v * 8];
        float f[8];
        #pragma unroll
        for (int j = 0; j < 8; ++j)
            f[j] = gelu_f(fmaf(bf2f(gv[j]), scale, shift));
        const unsigned r0 = cvt_pk_bf16(f[0], f[1]);
        const unsigned r1 = cvt_pk_bf16(f[2], f[3]);
        const unsigned r2 = cvt_pk_bf16(f[4], f[5]);
        const unsigned r3 = cvt_pk_bf16(f[6], f[7]);
        *(uint4*)&g[(size_t)v * 8] = make_uint4(r0, r1, r2, r3);
    }
}

// ---- K3: shift-stage g -> 2 GEMMs -> gelu+add -> h2 bf16 + GN2 partials ----
__global__ __launch_bounds__(256) void k_mid(
        const unsigned short* __restrict__ g,
        const unsigned short* __restrict__ BpA, const unsigned short* __restrict__ BpB,
        const float* __restrict__ b21, const float* __restrict__ b22,
        unsigned short* __restrict__ h2, float* __restrict__ part) {
    __shared__ unsigned short smem[2 * 64 * APITCH];
    unsigned short* Alr = smem;
    unsigned short* Atd = smem + 64 * APITCH;
    unsigned short* Tsd = smem;

    const int b = blockIdx.y;
    const int hw0 = blockIdx.x * PIX;
    const int wid = __builtin_amdgcn_readfirstlane(threadIdx.x >> 6);
    const int lane = threadIdx.x & 63;

    const unsigned short* gg = g + (size_t)b * CCH * HWSZ;
    const int hw = hw0 + lane;
    const int h = hw / WW, w = hw % WW;

    #pragma unroll
    for (int i = 0; i < 24; i += 2) {
        const int c = wid * 24 + i;
        const int d = (c < 32) ? 1 : (c < 64) ? 0 : -1;
        const size_t cb = (size_t)c * HWSZ + hw;
        unsigned lr, td;
        if (d == 0) {
            const unsigned v0 = gg[cb], v1 = gg[cb + HWSZ];
            lr = v0 | (v1 << 16);
            td = lr;
        } else {
            const bool okL = (d == 1) ? (w < WW - 1) : (w > 0);
            const bool okT = (d == 1) ? (h < HH - 1) : (h > 0);
            const int offL = okL ? d : 0;
            const int offT = okT ? d * WW : 0;
            unsigned l0 = gg[cb + offL], l1 = gg[cb + HWSZ + offL];
            unsigned t0 = gg[cb + offT], t1 = gg[cb + HWSZ + offT];
            l0 = okL ? l0 : 0u;  l1 = okL ? l1 : 0u;
            t0 = okT ? t0 : 0u;  t1 = okT ? t1 : 0u;
            lr = l0 | (l1 << 16);
            td = t0 | (t1 << 16);
        }
        *(unsigned*)&Alr[lane * APITCH + c] = lr;
        *(unsigned*)&Atd[lane * APITCH + c] = td;
    }
    __syncthreads();

    bf16x8 alr[3], atd[3];
    const int arow = (wid * 16 + (lane & 15)) * APITCH;
    const int acol = (lane >> 4) * 8;
    #pragma unroll
    for (int k0 = 0; k0 < 3; ++k0) {
        alr[k0] = *(const bf16x8*)&Alr[arow + k0 * 32 + acol];
        atd[k0] = *(const bf16x8*)&Atd[arow + k0 * 32 + acol];
    }
    __syncthreads();

    f32x4 accA[6], accB[6];
    #pragma unroll
    for (int n0 = 0; n0 < 6; ++n0) {
        const float biasA = b21[n0 * 16 + (lane & 15)];
        const float biasB = b22[n0 * 16 + (lane & 15)];
        accA[n0] = (f32x4){biasA, biasA, biasA, biasA};
        accB[n0] = (f32x4){biasB, biasB, biasB, biasB};
        #pragma unroll
        for (int k0 = 0; k0 < 3; ++k0) {
            const bf16x8 bA = *(const bf16x8*)(BpA + (n0 * 3 + k0) * 512 + lane * 8);
            const bf16x8 bB = *(const bf16x8*)(BpB + (n0 * 3 + k0) * 512 + lane * 8);
            accA[n0] = __builtin_amdgcn_mfma_f32_16x16x32_bf16(alr[k0], bA, accA[n0], 0, 0, 0);
            accB[n0] = __builtin_amdgcn_mfma_f32_16x16x32_bf16(atd[k0], bB, accB[n0], 0, 0, 0);
        }
    }

    float sum = 0.f, sumsq = 0.f;
    const int p0 = wid * 16 + (lane >> 4) * 4;
    #pragma unroll
    for (int n0 = 0; n0 < 6; ++n0) {
        const int o = n0 * 16 + (lane & 15);
        float vv[4];
        #pragma unroll
        for (int r = 0; r < 4; ++r) {
            const float v = gelu_f(accA[n0][r]) + gelu_f(accB[n0][r]);
            sum += v; sumsq += v * v;
            vv[r] = v;
        }
        const unsigned lo = cvt_pk_bf16(vv[0], vv[1]);
        const unsigned hi = cvt_pk_bf16(vv[2], vv[3]);
        *(uint2*)&Tsd[o * TPITCH + p0] = make_uint2(lo, hi);
    }
    __syncthreads();

    unsigned short* ob = h2 + (size_t)b * CCH * HWSZ + hw0;
    #pragma unroll
    for (int it = 0; it < 6; ++it) {
        const int o = it * 16 + (threadIdx.x >> 4);
        const int p = (threadIdx.x & 15) * 4;
        *(unsigned long long*)&ob[(size_t)o * HWSZ + p] =
            *(const unsigned long long*)&Tsd[o * TPITCH + p];
    }
    block_reduce_write(sum, sumsq, part, b * NBLK + blockIdx.x);
}

// ---- K5: gn2 affine -> conv3 -> out fp32 ----
__global__ __launch_bounds__(256) void k_out(
        const unsigned short* __restrict__ h2, const unsigned short* __restrict__ Bp,
        const float* __restrict__ b3, const float* __restrict__ ms2,
        const float* __restrict__ gw, const float* __restrict__ gb,
        float* __restrict__ out) {
    __shared__ float smemf[96 * TPITCHF];
    unsigned short* Asd = (unsigned short*)smemf;
    float* Tf = smemf;

    const int b = blockIdx.y;
    const int hw0 = blockIdx.x * PIX;
    const int wid = __builtin_amdgcn_readfirstlane(threadIdx.x >> 6);
    const int lane = threadIdx.x & 63;

    const float mu = ms2[2 * b + 0];
    const float inv = ms2[2 * b + 1];
    const unsigned short* hb = h2 + (size_t)b * CCH * HWSZ + hw0;
    #pragma unroll
    for (int i = 0; i < 24; i += 2) {
        const int c = wid * 24 + i;
        float v01[2];
        #pragma unroll
        for (int q = 0; q < 2; ++q) {
            const int cc = c + q;
            const float scale = inv * gw[cc];
            const float shift = gb[cc] - mu * scale;
            v01[q] = fmaf(bf2f(hb[(size_t)cc * HWSZ + lane]), scale, shift);
        }
        *(unsigned*)&Asd[lane * APITCH + c] = cvt_pk_bf16(v01[0], v01[1]);
    }
    __syncthreads();

    bf16x8 a[3];
    const int arow = (wid * 16 + (lane & 15)) * APITCH;
    const int acol = (lane >> 4) * 8;
    #pragma unroll
    for (int k0 = 0; k0 < 3; ++k0)
        a[k0] = *(const bf16x8*)&Asd[arow + k0 * 32 + acol];
    __syncthreads();

    f32x4 acc[6];
    #pragma unroll
    for (int n0 = 0; n0 < 6; ++n0) {
        const float bias = b3[n0 * 16 + (lane & 15)];
        acc[n0] = (f32x4){bias, bias, bias, bias};
        #pragma unroll
        for (int k0 = 0; k0 < 3; ++k0) {
            const bf16x8 bf = *(const bf16x8*)(Bp + (n0 * 3 + k0) * 512 + lane * 8);
            acc[n0] = __builtin_amdgcn_mfma_f32_16x16x32_bf16(a[k0], bf, acc[n0], 0, 0, 0);
        }
    }

    const int p0 = wid * 16 + (lane >> 4) * 4;
    #pragma unroll
    for (int n0 = 0; n0 < 6; ++n0) {
        const int o = n0 * 16 + (lane & 15);
        *(f32x4*)&Tf[o * TPITCHF + p0] = acc[n0];
    }
    __syncthreads();

    float* op = out + (size_t)b * CCH * HWSZ + hw0;
    #pragma unroll
    for (int it = 0; it < 12; ++it) {
        const int o = it * 8 + (threadIdx.x >> 5);
        const int p = (threadIdx.x & 31) * 2;
        *(float2*)&op[(size_t)o * HWSZ + p] = *(const float2*)&Tf[o * TPITCHF + p];
    }
}

extern "C" void kernel_launch(void* const* d_in, const int* in_sizes, int n_in,
                              void* d_out, int out_size, void* d_ws, size_t ws_size,
                              hipStream_t stream) {
    const float* x    = (const float*)d_in[0];
    const float* w1   = (const float*)d_in[1];
    const float* b1   = (const float*)d_in[2];
    const float* w21  = (const float*)d_in[3];
    const float* b21  = (const float*)d_in[4];
    const float* w22  = (const float*)d_in[5];
    const float* b22  = (const float*)d_in[6];
    const float* w3   = (const float*)d_in[7];
    const float* b3   = (const float*)d_in[8];
    const float* gn1w = (const float*)d_in[9];
    const float* gn1b = (const float*)d_in[10];
    const float* gn2w = (const float*)d_in[11];
    const float* gn2b = (const float*)d_in[12];

    char* base = (char*)d_ws;
    unsigned short* Bp   = (unsigned short*)base;            // 73728 B
    float*          part = (float*)(base + 73728);           // 50176 B
    float*          ms1  = (float*)(base + 123904);          // 64 f
    float*          ms2  = (float*)(base + 124160);          // 64 f
    unsigned short* h2   = (unsigned short*)(base + 131072); // 77 MB bf16
    unsigned short* h1   = (unsigned short*)d_out;           // h1, then g (in-place)

    dim3 grid(NBLK, NB), blk(256);
    k_prep<<<dim3(144), blk, 0, stream>>>(w1, w21, w22, w3, Bp);
    k_conv1<<<grid, blk, 0, stream>>>(x, Bp, b1, h1, part);
    k_stats<<<dim3(NB), dim3(64), 0, stream>>>(part, ms1);
    k_gact<<<dim3(2048), blk, 0, stream>>>(h1, ms1, gn1w, gn1b);
    k_mid<<<grid, blk, 0, stream>>>(h1, Bp + 18 * 512, Bp + 36 * 512,
                                    b21, b22, h2, part);
    k_stats<<<dim3(NB), dim3(64), 0, stream>>>(part, ms2);
    k_out<<<grid, blk, 0, stream>>>(h2, Bp + 54 * 512, b3, ms2, gn2w, gn2b, (float*)d_out);
}

// Round 7
// 206.393 us; speedup vs baseline: 7.9982x; 1.0657x over previous
//
#include <hip/hip_runtime.h>
#include <math.h>

#define CCH 96
#define HH 112
#define WW 112
#define HWSZ 12544      // 112*112
#define NB 32
#define PIX 64
#define NBLK 196        // 12544/64
#define EPSV 1e-5f
#define APITCH 120      // bf16 elems per A-row in conv1 staging LDS
#define TPITCH 72       // bf16 transpose pitch [96 ch][72 pix]
#define TPITCHF 68      // f32 transpose pitch in k_out
#define ROWC 96         // channels per pixel-major row

typedef __attribute__((ext_vector_type(8))) short bf16x8;
typedef __attribute__((ext_vector_type(4))) float f32x4;
typedef __attribute__((ext_vector_type(8))) unsigned short u16x8;

__device__ __forceinline__ unsigned short f2bf(float f) {
    union { float f; unsigned u; } v; v.f = f;
    unsigned r = v.u + 0x7fffu + ((v.u >> 16) & 1u);   // RTNE
    return (unsigned short)(r >> 16);
}
__device__ __forceinline__ float bf2f(unsigned short h) {
    union { unsigned u; float f; } v; v.u = ((unsigned)h) << 16;
    return v.f;
}
__device__ __forceinline__ unsigned cvt_pk_bf16(float lo, float hi) {
    unsigned r;
    asm("v_cvt_pk_bf16_f32 %0, %1, %2" : "=v"(r) : "v"(lo), "v"(hi));
    return r;
}
// tanh-form GELU via hw exp2/rcp (validated rounds 5-6)
__device__ __forceinline__ float gelu_f(float x) {
    const float K = 2.3022082f;
    float u = x * x;
    float p = x * fmaf(0.044715f, u, 1.0f);
    float e = __builtin_amdgcn_exp2f(p * K);
    float r = __builtin_amdgcn_rcpf(e + 1.0f);
    return x - x * r;
}

__device__ __forceinline__ void block_reduce_write(float sum, float sumsq,
                                                   float* part, int slot) {
    #pragma unroll
    for (int off = 32; off > 0; off >>= 1) {
        sum += __shfl_down(sum, off);
        sumsq += __shfl_down(sumsq, off);
    }
    __shared__ float ls[8];
    const int wid = threadIdx.x >> 6, lane = threadIdx.x & 63;
    if (lane == 0) { ls[wid] = sum; ls[4 + wid] = sumsq; }
    __syncthreads();
    if (threadIdx.x == 0) {
        part[slot * 2 + 0] = ls[0] + ls[1] + ls[2] + ls[3];
        part[slot * 2 + 1] = ls[4] + ls[5] + ls[6] + ls[7];
    }
}

// ---- weight prep: fp32 [O][C] -> bf16 fragment layout [m][n0][k0][lane][8] ----
__global__ void k_prep(const float* __restrict__ w1, const float* __restrict__ w21,
                       const float* __restrict__ w22,
                       unsigned short* __restrict__ Bp) {
    const int t = blockIdx.x * 256 + threadIdx.x;   // 3*18*512 = 27648
    if (t >= 3 * 18 * 512) return;
    const int j  = t & 7;
    const int l  = (t >> 3) & 63;
    const int s  = t >> 9;
    const int k0 = s % 3;
    const int n0 = (s / 3) % 6;
    const int m  = s / 18;
    const float* w = (m == 0) ? w1 : (m == 1) ? w21 : w22;
    const int n = n0 * 16 + (l & 15);
    const int k = k0 * 32 + (l >> 4) * 8 + j;
    Bp[t] = f2bf(w[n * CCH + k]);
}

// ---- K1: conv1 (x fp32 channel-major -> h1 bf16 PIXEL-major) + GN1 partials
__global__ __launch_bounds__(256) void k_conv1(
        const float* __restrict__ x, const unsigned short* __restrict__ Bp,
        const float* __restrict__ b1, unsigned short* __restrict__ h1t,
        float* __restrict__ part) {
    __shared__ unsigned short smem[64 * APITCH];   // 15360 B; Tsd (13824 B) reuses
    unsigned short* Asd = smem;
    unsigned short* Tsd = smem;

    const int b = blockIdx.y;
    const int hw0 = blockIdx.x * PIX;
    const int wid = __builtin_amdgcn_readfirstlane(threadIdx.x >> 6);
    const int lane = threadIdx.x & 63;

    const float* xb = x + (size_t)b * CCH * HWSZ + hw0;
    #pragma unroll
    for (int i = 0; i < 24; i += 2) {
        const int c = wid * 24 + i;
        *(unsigned*)&Asd[lane * APITCH + c] =
            cvt_pk_bf16(xb[(size_t)c * HWSZ + lane], xb[(size_t)(c + 1) * HWSZ + lane]);
    }
    __syncthreads();

    bf16x8 a[3];
    const int arow = (wid * 16 + (lane & 15)) * APITCH;
    const int acol = (lane >> 4) * 8;
    #pragma unroll
    for (int k0 = 0; k0 < 3; ++k0)
        a[k0] = *(const bf16x8*)&Asd[arow + k0 * 32 + acol];
    __syncthreads();

    f32x4 acc[6];
    #pragma unroll
    for (int n0 = 0; n0 < 6; ++n0) {
        const float bias = b1[n0 * 16 + (lane & 15)];
        acc[n0] = (f32x4){bias, bias, bias, bias};
        #pragma unroll
        for (int k0 = 0; k0 < 3; ++k0) {
            const bf16x8 bf = *(const bf16x8*)(Bp + (n0 * 3 + k0) * 512 + lane * 8);
            acc[n0] = __builtin_amdgcn_mfma_f32_16x16x32_bf16(a[k0], bf, acc[n0], 0, 0, 0);
        }
    }

    float sum = 0.f, sumsq = 0.f;
    const int p0 = wid * 16 + (lane >> 4) * 4;
    #pragma unroll
    for (int n0 = 0; n0 < 6; ++n0) {
        const int o = n0 * 16 + (lane & 15);
        #pragma unroll
        for (int r = 0; r < 4; ++r) {
            const float v = acc[n0][r];
            sum += v; sumsq += v * v;
        }
        const unsigned lo = cvt_pk_bf16(acc[n0][0], acc[n0][1]);
        const unsigned hi = cvt_pk_bf16(acc[n0][2], acc[n0][3]);
        *(uint2*)&Tsd[o * TPITCH + p0] = make_uint2(lo, hi);
    }
    __syncthreads();

    // cooperative PIXEL-major store: rows hw0..hw0+63, 96 ch each
    unsigned short* ob = h1t + ((size_t)b * HWSZ + hw0) * ROWC;
    #pragma unroll
    for (int it = 0; it < 3; ++it) {
        const int u = threadIdx.x + it * 256;      // 0..767
        const int pr = u / 12;
        const int c16 = (u % 12) * 8;
        unsigned r0 = (unsigned)Tsd[(c16 + 0) * TPITCH + pr] |
                      ((unsigned)Tsd[(c16 + 1) * TPITCH + pr] << 16);
        unsigned r1 = (unsigned)Tsd[(c16 + 2) * TPITCH + pr] |
                      ((unsigned)Tsd[(c16 + 3) * TPITCH + pr] << 16);
        unsigned r2 = (unsigned)Tsd[(c16 + 4) * TPITCH + pr] |
                      ((unsigned)Tsd[(c16 + 5) * TPITCH + pr] << 16);
        unsigned r3 = (unsigned)Tsd[(c16 + 6) * TPITCH + pr] |
                      ((unsigned)Tsd[(c16 + 7) * TPITCH + pr] << 16);
        *(uint4*)&ob[(size_t)pr * ROWC + c16] = make_uint4(r0, r1, r2, r3);
    }
    block_reduce_write(sum, sumsq, part, b * NBLK + blockIdx.x);
}

// ---- stats: partials -> (mean, rsqrt(var+eps)) per sample ----
__global__ void k_stats(const float* __restrict__ part, float* __restrict__ ms) {
    const int b = blockIdx.x;
    const int t = threadIdx.x;
    float s = 0.f, q = 0.f;
    for (int i = t; i < NBLK; i += 64) {
        s += part[(b * NBLK + i) * 2 + 0];
        q += part[(b * NBLK + i) * 2 + 1];
    }
    #pragma unroll
    for (int off = 32; off > 0; off >>= 1) {
        s += __shfl_down(s, off);
        q += __shfl_down(q, off);
    }
    if (t == 0) {
        const float n = (float)CCH * (float)HWSZ;
        const float mu = s / n;
        const float var = q / n - mu * mu;
        ms[2 * b + 0] = mu;
        ms[2 * b + 1] = rsqrtf(var + EPSV);
    }
}

// ---- K2.5: g = gelu(gn1(h1)) elementwise in-place, pixel-major rows ----
__global__ __launch_bounds__(256) void k_gact(
        unsigned short* __restrict__ g, const float* __restrict__ ms,
        const float* __restrict__ gw, const float* __restrict__ gb) {
    const int b = blockIdx.y;
    __shared__ __align__(16) float ts[CCH];
    __shared__ __align__(16) float th[CCH];
    const int t = threadIdx.x;
    if (t < CCH) {
        const float sc = ms[2 * b + 1] * gw[t];
        ts[t] = sc;
        th[t] = gb[t] - ms[2 * b] * sc;
    }
    __syncthreads();
    unsigned short* gb_ = g + (size_t)b * HWSZ * ROWC;
    #pragma unroll
    for (int i = 0; i < 4; ++i) {
        const int v = blockIdx.x * 1024 + i * 256 + t;   // < 150528
        const int c0 = (v % 12) * 8;
        const u16x8 gv = *(const u16x8*)&gb_[(size_t)v * 8];
        const f32x4 s0 = *(const f32x4*)&ts[c0];
        const f32x4 s1 = *(const f32x4*)&ts[c0 + 4];
        const f32x4 h0 = *(const f32x4*)&th[c0];
        const f32x4 h1 = *(const f32x4*)&th[c0 + 4];
        float f[8];
        #pragma unroll
        for (int j = 0; j < 4; ++j) {
            f[j]     = gelu_f(fmaf(bf2f(gv[j]),     s0[j], h0[j]));
            f[j + 4] = gelu_f(fmaf(bf2f(gv[j + 4]), s1[j], h1[j]));
        }
        const unsigned r0 = cvt_pk_bf16(f[0], f[1]);
        const unsigned r1 = cvt_pk_bf16(f[2], f[3]);
        const unsigned r2 = cvt_pk_bf16(f[4], f[5]);
        const unsigned r3 = cvt_pk_bf16(f[6], f[7]);
        *(uint4*)&gb_[(size_t)v * 8] = make_uint4(r0, r1, r2, r3);
    }
}

// ---- K3: direct shifted frag loads -> 2 GEMMs -> gelu+add -> h2t + GN2 part
__global__ __launch_bounds__(256) void k_mid(
        const unsigned short* __restrict__ gt,
        const unsigned short* __restrict__ BpA, const unsigned short* __restrict__ BpB,
        const float* __restrict__ b21, const float* __restrict__ b22,
        unsigned short* __restrict__ h2t, float* __restrict__ part) {
    __shared__ unsigned short Tsd[CCH * TPITCH];   // 13824 B

    const int b = blockIdx.y;
    const int hw0 = blockIdx.x * PIX;
    const int wid = __builtin_amdgcn_readfirstlane(threadIdx.x >> 6);
    const int lane = threadIdx.x & 63;
    const int prow = hw0 + wid * 16 + (lane & 15);
    const int w = prow % WW;
    const int hrow = prow / WW;
    const int acol8 = (lane >> 4) * 8;
    const unsigned short* gb_ = gt + (size_t)b * HWSZ * ROWC;

    bf16x8 alr[3], atd[3];
    const bf16x8 zf = (bf16x8){0, 0, 0, 0, 0, 0, 0, 0};
    #pragma unroll
    for (int k0 = 0; k0 < 3; ++k0) {
        const int d = (k0 == 0) ? 1 : (k0 == 1) ? 0 : -1;
        if (d == 0) {
            bf16x8 f0 = *(const bf16x8*)(gb_ + (size_t)prow * ROWC + k0 * 32 + acol8);
            alr[k0] = f0;
            atd[k0] = f0;
        } else {
            const bool okL = (unsigned)(w + d) < WW;
            const bool okT = (unsigned)(hrow + d) < HH;
            const int pL = okL ? prow + d : prow;
            const int pT = okT ? prow + d * WW : prow;
            bf16x8 fl = *(const bf16x8*)(gb_ + (size_t)pL * ROWC + k0 * 32 + acol8);
            bf16x8 ft = *(const bf16x8*)(gb_ + (size_t)pT * ROWC + k0 * 32 + acol8);
            alr[k0] = okL ? fl : zf;
            atd[k0] = okT ? ft : zf;
        }
    }

    f32x4 accA[6], accB[6];
    #pragma unroll
    for (int n0 = 0; n0 < 6; ++n0) {
        const float biasA = b21[n0 * 16 + (lane & 15)];
        const float biasB = b22[n0 * 16 + (lane & 15)];
        accA[n0] = (f32x4){biasA, biasA, biasA, biasA};
        accB[n0] = (f32x4){biasB, biasB, biasB, biasB};
        #pragma unroll
        for (int k0 = 0; k0 < 3; ++k0) {
            const bf16x8 bA = *(const bf16x8*)(BpA + (n0 * 3 + k0) * 512 + lane * 8);
            const bf16x8 bB = *(const bf16x8*)(BpB + (n0 * 3 + k0) * 512 + lane * 8);
            accA[n0] = __builtin_amdgcn_mfma_f32_16x16x32_bf16(alr[k0], bA, accA[n0], 0, 0, 0);
            accB[n0] = __builtin_amdgcn_mfma_f32_16x16x32_bf16(atd[k0], bB, accB[n0], 0, 0, 0);
        }
    }

    float sum = 0.f, sumsq = 0.f;
    const int p0 = wid * 16 + (lane >> 4) * 4;
    #pragma unroll
    for (int n0 = 0; n0 < 6; ++n0) {
        const int o = n0 * 16 + (lane & 15);
        float vv[4];
        #pragma unroll
        for (int r = 0; r < 4; ++r) {
            const float v = gelu_f(accA[n0][r]) + gelu_f(accB[n0][r]);
            sum += v; sumsq += v * v;
            vv[r] = v;
        }
        const unsigned lo = cvt_pk_bf16(vv[0], vv[1]);
        const unsigned hi = cvt_pk_bf16(vv[2], vv[3]);
        *(uint2*)&Tsd[o * TPITCH + p0] = make_uint2(lo, hi);
    }
    __syncthreads();

    unsigned short* ob = h2t + ((size_t)b * HWSZ + hw0) * ROWC;
    #pragma unroll
    for (int it = 0; it < 3; ++it) {
        const int u = threadIdx.x + it * 256;
        const int pr = u / 12;
        const int c16 = (u % 12) * 8;
        unsigned r0 = (unsigned)Tsd[(c16 + 0) * TPITCH + pr] |
                      ((unsigned)Tsd[(c16 + 1) * TPITCH + pr] << 16);
        unsigned r1 = (unsigned)Tsd[(c16 + 2) * TPITCH + pr] |
                      ((unsigned)Tsd[(c16 + 3) * TPITCH + pr] << 16);
        unsigned r2 = (unsigned)Tsd[(c16 + 4) * TPITCH + pr] |
                      ((unsigned)Tsd[(c16 + 5) * TPITCH + pr] << 16);
        unsigned r3 = (unsigned)Tsd[(c16 + 6) * TPITCH + pr] |
                      ((unsigned)Tsd[(c16 + 7) * TPITCH + pr] << 16);
        *(uint4*)&ob[(size_t)pr * ROWC + c16] = make_uint4(r0, r1, r2, r3);
    }
    block_reduce_write(sum, sumsq, part, b * NBLK + blockIdx.x);
}

// ---- per-sample fold of GN2 into conv3: W3' = W3*scale, b3' = W3.shift + b3
__global__ void k_wprep(const float* __restrict__ w3, const float* __restrict__ b3,
                        const float* __restrict__ ms2,
                        const float* __restrict__ gw, const float* __restrict__ gb,
                        unsigned short* __restrict__ W3p, float* __restrict__ biasp) {
    const int b = blockIdx.x;
    __shared__ float ts[CCH], th[CCH];
    const int t = threadIdx.x;
    if (t < CCH) {
        const float sc = ms2[2 * b + 1] * gw[t];
        ts[t] = sc;
        th[t] = gb[t] - ms2[2 * b] * sc;
    }
    __syncthreads();
    unsigned short* Wb = W3p + b * 9216;
    #pragma unroll
    for (int i = 0; i < 36; ++i) {
        const int idx = t + i * 256;               // < 9216
        const int j = idx & 7;
        const int l = (idx >> 3) & 63;
        const int s = idx >> 9;
        const int k0 = s % 3, n0 = s / 3;
        const int n = n0 * 16 + (l & 15);
        const int k = k0 * 32 + (l >> 4) * 8 + j;
        Wb[idx] = f2bf(w3[n * CCH + k] * ts[k]);
    }
    if (t < CCH) {
        float a = b3[t];
        for (int c = 0; c < CCH; ++c) a = fmaf(w3[t * CCH + c], th[c], a);
        biasp[b * CCH + t] = a;
    }
}

// ---- K5: raw frag loads from h2t -> conv3' -> out fp32 channel-major ----
__global__ __launch_bounds__(256) void k_out(
        const unsigned short* __restrict__ h2t, const unsigned short* __restrict__ W3p,
        const float* __restrict__ biasp, float* __restrict__ out) {
    __shared__ float Tf[CCH * TPITCHF];   // 26112 B

    const int b = blockIdx.y;
    const int hw0 = blockIdx.x * PIX;
    const int wid = __builtin_amdgcn_readfirstlane(threadIdx.x >> 6);
    const int lane = threadIdx.x & 63;
    const int prow = hw0 + wid * 16 + (lane & 15);
    const int acol8 = (lane >> 4) * 8;

    const unsigned short* hb = h2t + (size_t)b * HWSZ * ROWC;
    bf16x8 a[3];
    #pragma unroll
    for (int k0 = 0; k0 < 3; ++k0)
        a[k0] = *(const bf16x8*)(hb + (size_t)prow * ROWC + k0 * 32 + acol8);

    const unsigned short* Bb = W3p + b * 9216;
    f32x4 acc[6];
    #pragma unroll
    for (int n0 = 0; n0 < 6; ++n0) {
        const float bias = biasp[b * CCH + n0 * 16 + (lane & 15)];
        acc[n0] = (f32x4){bias, bias, bias, bias};
        #pragma unroll
        for (int k0 = 0; k0 < 3; ++k0) {
            const bf16x8 bf = *(const bf16x8*)(Bb + (n0 * 3 + k0) * 512 + lane * 8);
            acc[n0] = __builtin_amdgcn_mfma_f32_16x16x32_bf16(a[k0], bf, acc[n0], 0, 0, 0);
        }
    }

    const int p0 = wid * 16 + (lane >> 4) * 4;
    #pragma unroll
    for (int n0 = 0; n0 < 6; ++n0) {
        const int o = n0 * 16 + (lane & 15);
        *(f32x4*)&Tf[o * TPITCHF + p0] = acc[n0];
    }
    __syncthreads();

    float* op = out + (size_t)b * CCH * HWSZ + hw0;
    #pragma unroll
    for (int it = 0; it < 12; ++it) {
        const int o = it * 8 + (threadIdx.x >> 5);
        const int p = (threadIdx.x & 31) * 2;
        *(float2*)&op[(size_t)o * HWSZ + p] = *(const float2*)&Tf[o * TPITCHF + p];
    }
}

extern "C" void kernel_launch(void* const* d_in, const int* in_sizes, int n_in,
                              void* d_out, int out_size, void* d_ws, size_t ws_size,
                              hipStream_t stream) {
    const float* x    = (const float*)d_in[0];
    const float* w1   = (const float*)d_in[1];
    const float* b1   = (const float*)d_in[2];
    const float* w21  = (const float*)d_in[3];
    const float* b21  = (const float*)d_in[4];
    const float* w22  = (const float*)d_in[5];
    const float* b22  = (const float*)d_in[6];
    const float* w3   = (const float*)d_in[7];
    const float* b3   = (const float*)d_in[8];
    const float* gn1w = (const float*)d_in[9];
    const float* gn1b = (const float*)d_in[10];
    const float* gn2w = (const float*)d_in[11];
    const float* gn2b = (const float*)d_in[12];

    char* base = (char*)d_ws;
    unsigned short* Bp    = (unsigned short*)base;             // 27648 bf16 = 55296 B
    float*          part  = (float*)(base + 73728);            // 50176 B
    float*          ms1   = (float*)(base + 123904);           // 64 f
    float*          ms2   = (float*)(base + 124160);           // 64 f
    unsigned short* W3p   = (unsigned short*)(base + 131072);  // 589824 B
    float*          biasp = (float*)(base + 720896);           // 12288 B
    unsigned short* h2t   = (unsigned short*)(base + 1048576); // 77 MB bf16
    unsigned short* h1t   = (unsigned short*)d_out;            // h1t, then g (in-place)

    dim3 grid(NBLK, NB), blk(256);
    k_prep<<<dim3(108), blk, 0, stream>>>(w1, w21, w22, Bp);
    k_conv1<<<grid, blk, 0, stream>>>(x, Bp, b1, h1t, part);
    k_stats<<<dim3(NB), dim3(64), 0, stream>>>(part, ms1);
    k_gact<<<dim3(147, NB), blk, 0, stream>>>(h1t, ms1, gn1w, gn1b);
    k_mid<<<grid, blk, 0, stream>>>(h1t, Bp + 18 * 512, Bp + 36 * 512,
                                    b21, b22, h2t, part);
    k_stats<<<dim3(NB), dim3(64), 0, stream>>>(part, ms2);
    k_wprep<<<dim3(NB), blk, 0, stream>>>(w3, b3, ms2, gn2w, gn2b, W3p, biasp);
    k_out<<<grid, blk, 0, stream>>>(h2t, W3p, biasp, (float*)d_out);
}

// Round 8
// 202.245 us; speedup vs baseline: 8.1623x; 1.0205x over previous
//
#include <hip/hip_runtime.h>
#include <math.h>

#define CCH 96
#define HH 112
#define WW 112
#define HWSZ 12544      // 112*112
#define NB 32
#define PIX 64
#define NBLK 196        // 12544/64
#define EPSV 1e-5f
#define APITCH 120      // bf16 elems per A-row in conv1 staging LDS
#define TPITCH 72       // bf16 transpose pitch [96 ch][72 pix]
#define TPITCHF 68      // f32 transpose pitch in k_out
#define ROWC 96         // channels per pixel-major row

typedef __attribute__((ext_vector_type(8))) short bf16x8;
typedef __attribute__((ext_vector_type(4))) float f32x4;
typedef __attribute__((ext_vector_type(8))) unsigned short u16x8;

__device__ __forceinline__ unsigned short f2bf(float f) {
    union { float f; unsigned u; } v; v.f = f;
    unsigned r = v.u + 0x7fffu + ((v.u >> 16) & 1u);   // RTNE
    return (unsigned short)(r >> 16);
}
__device__ __forceinline__ float bf2f(unsigned short h) {
    union { unsigned u; float f; } v; v.u = ((unsigned)h) << 16;
    return v.f;
}
__device__ __forceinline__ unsigned cvt_pk_bf16(float lo, float hi) {
    unsigned r;
    asm("v_cvt_pk_bf16_f32 %0, %1, %2" : "=v"(r) : "v"(lo), "v"(hi));
    return r;
}
// tanh-form GELU via hw exp2/rcp (validated rounds 5-7)
__device__ __forceinline__ float gelu_f(float x) {
    const float K = 2.3022082f;
    float u = x * x;
    float p = x * fmaf(0.044715f, u, 1.0f);
    float e = __builtin_amdgcn_exp2f(p * K);
    float r = __builtin_amdgcn_rcpf(e + 1.0f);
    return x - x * r;
}

__device__ __forceinline__ void block_reduce_write(float sum, float sumsq,
                                                   float* part, int slot) {
    #pragma unroll
    for (int off = 32; off > 0; off >>= 1) {
        sum += __shfl_down(sum, off);
        sumsq += __shfl_down(sumsq, off);
    }
    __shared__ float ls[8];
    const int wid = threadIdx.x >> 6, lane = threadIdx.x & 63;
    if (lane == 0) { ls[wid] = sum; ls[4 + wid] = sumsq; }
    __syncthreads();
    if (threadIdx.x == 0) {
        part[slot * 2 + 0] = ls[0] + ls[1] + ls[2] + ls[3];
        part[slot * 2 + 1] = ls[4] + ls[5] + ls[6] + ls[7];
    }
}

// wave-0 reduce of one sample's 196 partial pairs -> (mu, inv) in shared
__device__ __forceinline__ void stats_reduce(const float* __restrict__ part,
                                             int b, float* sh_mu, float* sh_inv) {
    const int t = threadIdx.x;
    if (t < 64) {
        float s = 0.f, q = 0.f;
        for (int i = t; i < NBLK; i += 64) {
            s += part[(b * NBLK + i) * 2 + 0];
            q += part[(b * NBLK + i) * 2 + 1];
        }
        #pragma unroll
        for (int off = 32; off > 0; off >>= 1) {
            s += __shfl_down(s, off);
            q += __shfl_down(q, off);
        }
        if (t == 0) {
            const float n = (float)CCH * (float)HWSZ;
            const float mu = s / n;
            const float var = q / n - mu * mu;
            *sh_mu = mu;
            *sh_inv = rsqrtf(var + EPSV);
        }
    }
}

// ---- weight prep: fp32 [O][C] -> bf16 fragment layout [m][n0][k0][lane][8] ----
__global__ void k_prep(const float* __restrict__ w1, const float* __restrict__ w21,
                       const float* __restrict__ w22,
                       unsigned short* __restrict__ Bp) {
    const int t = blockIdx.x * 256 + threadIdx.x;   // 3*18*512 = 27648
    if (t >= 3 * 18 * 512) return;
    const int j  = t & 7;
    const int l  = (t >> 3) & 63;
    const int s  = t >> 9;
    const int k0 = s % 3;
    const int n0 = (s / 3) % 6;
    const int m  = s / 18;
    const float* w = (m == 0) ? w1 : (m == 1) ? w21 : w22;
    const int n = n0 * 16 + (l & 15);
    const int k = k0 * 32 + (l >> 4) * 8 + j;
    Bp[t] = f2bf(w[n * CCH + k]);
}

// ---- K1: conv1 (x fp32 channel-major -> h1 bf16 PIXEL-major) + GN1 partials
__global__ __launch_bounds__(256) void k_conv1(
        const float* __restrict__ x, const unsigned short* __restrict__ Bp,
        const float* __restrict__ b1, unsigned short* __restrict__ h1t,
        float* __restrict__ part) {
    __shared__ unsigned short smem[64 * APITCH];   // 15360 B; Tsd (13824 B) reuses
    unsigned short* Asd = smem;
    unsigned short* Tsd = smem;

    const int b = blockIdx.y;
    const int hw0 = blockIdx.x * PIX;
    const int wid = __builtin_amdgcn_readfirstlane(threadIdx.x >> 6);
    const int lane = threadIdx.x & 63;

    const float* xb = x + (size_t)b * CCH * HWSZ + hw0;
    #pragma unroll
    for (int i = 0; i < 24; i += 2) {
        const int c = wid * 24 + i;
        *(unsigned*)&Asd[lane * APITCH + c] =
            cvt_pk_bf16(xb[(size_t)c * HWSZ + lane], xb[(size_t)(c + 1) * HWSZ + lane]);
    }
    __syncthreads();

    bf16x8 a[3];
    const int arow = (wid * 16 + (lane & 15)) * APITCH;
    const int acol = (lane >> 4) * 8;
    #pragma unroll
    for (int k0 = 0; k0 < 3; ++k0)
        a[k0] = *(const bf16x8*)&Asd[arow + k0 * 32 + acol];
    __syncthreads();

    f32x4 acc[6];
    #pragma unroll
    for (int n0 = 0; n0 < 6; ++n0) {
        const float bias = b1[n0 * 16 + (lane & 15)];
        acc[n0] = (f32x4){bias, bias, bias, bias};
        #pragma unroll
        for (int k0 = 0; k0 < 3; ++k0) {
            const bf16x8 bf = *(const bf16x8*)(Bp + (n0 * 3 + k0) * 512 + lane * 8);
            acc[n0] = __builtin_amdgcn_mfma_f32_16x16x32_bf16(a[k0], bf, acc[n0], 0, 0, 0);
        }
    }

    float sum = 0.f, sumsq = 0.f;
    const int p0 = wid * 16 + (lane >> 4) * 4;
    #pragma unroll
    for (int n0 = 0; n0 < 6; ++n0) {
        const int o = n0 * 16 + (lane & 15);
        #pragma unroll
        for (int r = 0; r < 4; ++r) {
            const float v = acc[n0][r];
            sum += v; sumsq += v * v;
        }
        const unsigned lo = cvt_pk_bf16(acc[n0][0], acc[n0][1]);
        const unsigned hi = cvt_pk_bf16(acc[n0][2], acc[n0][3]);
        *(uint2*)&Tsd[o * TPITCH + p0] = make_uint2(lo, hi);
    }
    __syncthreads();

    // cooperative PIXEL-major store: rows hw0..hw0+63, 96 ch each
    unsigned short* ob = h1t + ((size_t)b * HWSZ + hw0) * ROWC;
    #pragma unroll
    for (int it = 0; it < 3; ++it) {
        const int u = threadIdx.x + it * 256;      // 0..767
        const int pr = u / 12;
        const int c16 = (u % 12) * 8;
        unsigned r0 = (unsigned)Tsd[(c16 + 0) * TPITCH + pr] |
                      ((unsigned)Tsd[(c16 + 1) * TPITCH + pr] << 16);
        unsigned r1 = (unsigned)Tsd[(c16 + 2) * TPITCH + pr] |
                      ((unsigned)Tsd[(c16 + 3) * TPITCH + pr] << 16);
        unsigned r2 = (unsigned)Tsd[(c16 + 4) * TPITCH + pr] |
                      ((unsigned)Tsd[(c16 + 5) * TPITCH + pr] << 16);
        unsigned r3 = (unsigned)Tsd[(c16 + 6) * TPITCH + pr] |
                      ((unsigned)Tsd[(c16 + 7) * TPITCH + pr] << 16);
        *(uint4*)&ob[(size_t)pr * ROWC + c16] = make_uint4(r0, r1, r2, r3);
    }
    block_reduce_write(sum, sumsq, part, b * NBLK + blockIdx.x);
}

// ---- K2: g = gelu(gn1(h1)) elementwise in-place, stats folded in ----
__global__ __launch_bounds__(256) void k_gact(
        unsigned short* __restrict__ g, const float* __restrict__ part,
        const float* __restrict__ gw, const float* __restrict__ gb) {
    const int b = blockIdx.y;
    __shared__ __align__(16) float ts[CCH];
    __shared__ __align__(16) float th[CCH];
    __shared__ float sh_mu, sh_inv;
    stats_reduce(part, b, &sh_mu, &sh_inv);
    __syncthreads();
    const int t = threadIdx.x;
    if (t < CCH) {
        const float sc = sh_inv * gw[t];
        ts[t] = sc;
        th[t] = gb[t] - sh_mu * sc;
    }
    __syncthreads();
    unsigned short* gb_ = g + (size_t)b * HWSZ * ROWC;
    #pragma unroll
    for (int i = 0; i < 4; ++i) {
        const int v = blockIdx.x * 1024 + i * 256 + t;   // < 150528
        const int c0 = (v % 12) * 8;
        const u16x8 gv = *(const u16x8*)&gb_[(size_t)v * 8];
        const f32x4 s0 = *(const f32x4*)&ts[c0];
        const f32x4 s1 = *(const f32x4*)&ts[c0 + 4];
        const f32x4 h0 = *(const f32x4*)&th[c0];
        const f32x4 h1 = *(const f32x4*)&th[c0 + 4];
        float f[8];
        #pragma unroll
        for (int j = 0; j < 4; ++j) {
            f[j]     = gelu_f(fmaf(bf2f(gv[j]),     s0[j], h0[j]));
            f[j + 4] = gelu_f(fmaf(bf2f(gv[j + 4]), s1[j], h1[j]));
        }
        const unsigned r0 = cvt_pk_bf16(f[0], f[1]);
        const unsigned r1 = cvt_pk_bf16(f[2], f[3]);
        const unsigned r2 = cvt_pk_bf16(f[4], f[5]);
        const unsigned r3 = cvt_pk_bf16(f[6], f[7]);
        *(uint4*)&gb_[(size_t)v * 8] = make_uint4(r0, r1, r2, r3);
    }
}

// ---- K3: direct shifted frag loads -> 2 GEMMs -> gelu+add -> h2t + GN2 part
__global__ __launch_bounds__(256) void k_mid(
        const unsigned short* __restrict__ gt,
        const unsigned short* __restrict__ BpA, const unsigned short* __restrict__ BpB,
        const float* __restrict__ b21, const float* __restrict__ b22,
        unsigned short* __restrict__ h2t, float* __restrict__ part) {
    __shared__ unsigned short Tsd[CCH * TPITCH];   // 13824 B

    const int b = blockIdx.y;
    const int hw0 = blockIdx.x * PIX;
    const int wid = __builtin_amdgcn_readfirstlane(threadIdx.x >> 6);
    const int lane = threadIdx.x & 63;
    const int prow = hw0 + wid * 16 + (lane & 15);
    const int w = prow % WW;
    const int hrow = prow / WW;
    const int acol8 = (lane >> 4) * 8;
    const unsigned short* gb_ = gt + (size_t)b * HWSZ * ROWC;

    bf16x8 alr[3], atd[3];
    const bf16x8 zf = (bf16x8){0, 0, 0, 0, 0, 0, 0, 0};
    #pragma unroll
    for (int k0 = 0; k0 < 3; ++k0) {
        const int d = (k0 == 0) ? 1 : (k0 == 1) ? 0 : -1;
        if (d == 0) {
            bf16x8 f0 = *(const bf16x8*)(gb_ + (size_t)prow * ROWC + k0 * 32 + acol8);
            alr[k0] = f0;
            atd[k0] = f0;
        } else {
            const bool okL = (unsigned)(w + d) < WW;
            const bool okT = (unsigned)(hrow + d) < HH;
            const int pL = okL ? prow + d : prow;
            const int pT = okT ? prow + d * WW : prow;
            bf16x8 fl = *(const bf16x8*)(gb_ + (size_t)pL * ROWC + k0 * 32 + acol8);
            bf16x8 ft = *(const bf16x8*)(gb_ + (size_t)pT * ROWC + k0 * 32 + acol8);
            alr[k0] = okL ? fl : zf;
            atd[k0] = okT ? ft : zf;
        }
    }

    f32x4 accA[6], accB[6];
    #pragma unroll
    for (int n0 = 0; n0 < 6; ++n0) {
        const float biasA = b21[n0 * 16 + (lane & 15)];
        const float biasB = b22[n0 * 16 + (lane & 15)];
        accA[n0] = (f32x4){biasA, biasA, biasA, biasA};
        accB[n0] = (f32x4){biasB, biasB, biasB, biasB};
        #pragma unroll
        for (int k0 = 0; k0 < 3; ++k0) {
            const bf16x8 bA = *(const bf16x8*)(BpA + (n0 * 3 + k0) * 512 + lane * 8);
            const bf16x8 bB = *(const bf16x8*)(BpB + (n0 * 3 + k0) * 512 + lane * 8);
            accA[n0] = __builtin_amdgcn_mfma_f32_16x16x32_bf16(alr[k0], bA, accA[n0], 0, 0, 0);
            accB[n0] = __builtin_amdgcn_mfma_f32_16x16x32_bf16(atd[k0], bB, accB[n0], 0, 0, 0);
        }
    }

    float sum = 0.f, sumsq = 0.f;
    const int p0 = wid * 16 + (lane >> 4) * 4;
    #pragma unroll
    for (int n0 = 0; n0 < 6; ++n0) {
        const int o = n0 * 16 + (lane & 15);
        float vv[4];
        #pragma unroll
        for (int r = 0; r < 4; ++r) {
            const float v = gelu_f(accA[n0][r]) + gelu_f(accB[n0][r]);
            sum += v; sumsq += v * v;
            vv[r] = v;
        }
        const unsigned lo = cvt_pk_bf16(vv[0], vv[1]);
        const unsigned hi = cvt_pk_bf16(vv[2], vv[3]);
        *(uint2*)&Tsd[o * TPITCH + p0] = make_uint2(lo, hi);
    }
    __syncthreads();

    unsigned short* ob = h2t + ((size_t)b * HWSZ + hw0) * ROWC;
    #pragma unroll
    for (int it = 0; it < 3; ++it) {
        const int u = threadIdx.x + it * 256;
        const int pr = u / 12;
        const int c16 = (u % 12) * 8;
        unsigned r0 = (unsigned)Tsd[(c16 + 0) * TPITCH + pr] |
                      ((unsigned)Tsd[(c16 + 1) * TPITCH + pr] << 16);
        unsigned r1 = (unsigned)Tsd[(c16 + 2) * TPITCH + pr] |
                      ((unsigned)Tsd[(c16 + 3) * TPITCH + pr] << 16);
        unsigned r2 = (unsigned)Tsd[(c16 + 4) * TPITCH + pr] |
                      ((unsigned)Tsd[(c16 + 5) * TPITCH + pr] << 16);
        unsigned r3 = (unsigned)Tsd[(c16 + 6) * TPITCH + pr] |
                      ((unsigned)Tsd[(c16 + 7) * TPITCH + pr] << 16);
        *(uint4*)&ob[(size_t)pr * ROWC + c16] = make_uint4(r0, r1, r2, r3);
    }
    block_reduce_write(sum, sumsq, part, b * NBLK + blockIdx.x);
}

// ---- K4: per-sample GN2 fold into conv3 (stats folded in):
//      W3' = W3*scale, b3' = W3.shift + b3
__global__ void k_wprep(const float* __restrict__ w3, const float* __restrict__ b3,
                        const float* __restrict__ part,
                        const float* __restrict__ gw, const float* __restrict__ gb,
                        unsigned short* __restrict__ W3p, float* __restrict__ biasp) {
    const int b = blockIdx.x;
    __shared__ float ts[CCH], th[CCH];
    __shared__ float sh_mu, sh_inv;
    stats_reduce(part, b, &sh_mu, &sh_inv);
    __syncthreads();
    const int t = threadIdx.x;
    if (t < CCH) {
        const float sc = sh_inv * gw[t];
        ts[t] = sc;
        th[t] = gb[t] - sh_mu * sc;
    }
    __syncthreads();
    unsigned short* Wb = W3p + b * 9216;
    #pragma unroll
    for (int i = 0; i < 36; ++i) {
        const int idx = t + i * 256;               // < 9216
        const int j = idx & 7;
        const int l = (idx >> 3) & 63;
        const int s = idx >> 9;
        const int k0 = s % 3, n0 = s / 3;
        const int n = n0 * 16 + (l & 15);
        const int k = k0 * 32 + (l >> 4) * 8 + j;
        Wb[idx] = f2bf(w3[n * CCH + k] * ts[k]);
    }
    if (t < CCH) {
        float a = b3[t];
        for (int c = 0; c < CCH; ++c) a = fmaf(w3[t * CCH + c], th[c], a);
        biasp[b * CCH + t] = a;
    }
}

// ---- K5: raw frag loads from h2t -> conv3' -> out fp32 channel-major ----
__global__ __launch_bounds__(256) void k_out(
        const unsigned short* __restrict__ h2t, const unsigned short* __restrict__ W3p,
        const float* __restrict__ biasp, float* __restrict__ out) {
    __shared__ float Tf[CCH * TPITCHF];   // 26112 B

    const int b = blockIdx.y;
    const int hw0 = blockIdx.x * PIX;
    const int wid = __builtin_amdgcn_readfirstlane(threadIdx.x >> 6);
    const int lane = threadIdx.x & 63;
    const int prow = hw0 + wid * 16 + (lane & 15);
    const int acol8 = (lane >> 4) * 8;

    const unsigned short* hb = h2t + (size_t)b * HWSZ * ROWC;
    bf16x8 a[3];
    #pragma unroll
    for (int k0 = 0; k0 < 3; ++k0)
        a[k0] = *(const bf16x8*)(hb + (size_t)prow * ROWC + k0 * 32 + acol8);

    const unsigned short* Bb = W3p + b * 9216;
    f32x4 acc[6];
    #pragma unroll
    for (int n0 = 0; n0 < 6; ++n0) {
        const float bias = biasp[b * CCH + n0 * 16 + (lane & 15)];
        acc[n0] = (f32x4){bias, bias, bias, bias};
        #pragma unroll
        for (int k0 = 0; k0 < 3; ++k0) {
            const bf16x8 bf = *(const bf16x8*)(Bb + (n0 * 3 + k0) * 512 + lane * 8);
            acc[n0] = __builtin_amdgcn_mfma_f32_16x16x32_bf16(a[k0], bf, acc[n0], 0, 0, 0);
        }
    }

    const int p0 = wid * 16 + (lane >> 4) * 4;
    #pragma unroll
    for (int n0 = 0; n0 < 6; ++n0) {
        const int o = n0 * 16 + (lane & 15);
        *(f32x4*)&Tf[o * TPITCHF + p0] = acc[n0];
    }
    __syncthreads();

    float* op = out + (size_t)b * CCH * HWSZ + hw0;
    #pragma unroll
    for (int it = 0; it < 6; ++it) {
        const int o = it * 16 + (threadIdx.x >> 4);
        const int p = (threadIdx.x & 15) * 4;
        *(f32x4*)&op[(size_t)o * HWSZ + p] = *(const f32x4*)&Tf[o * TPITCHF + p];
    }
}

extern "C" void kernel_launch(void* const* d_in, const int* in_sizes, int n_in,
                              void* d_out, int out_size, void* d_ws, size_t ws_size,
                              hipStream_t stream) {
    const float* x    = (const float*)d_in[0];
    const float* w1   = (const float*)d_in[1];
    const float* b1   = (const float*)d_in[2];
    const float* w21  = (const float*)d_in[3];
    const float* b21  = (const float*)d_in[4];
    const float* w22  = (const float*)d_in[5];
    const float* b22  = (const float*)d_in[6];
    const float* w3   = (const float*)d_in[7];
    const float* b3   = (const float*)d_in[8];
    const float* gn1w = (const float*)d_in[9];
    const float* gn1b = (const float*)d_in[10];
    const float* gn2w = (const float*)d_in[11];
    const float* gn2b = (const float*)d_in[12];

    char* base = (char*)d_ws;
    unsigned short* Bp    = (unsigned short*)base;             // 27648 bf16 = 55296 B
    float*          part  = (float*)(base + 73728);            // 50176 B
    unsigned short* W3p   = (unsigned short*)(base + 131072);  // 589824 B
    float*          biasp = (float*)(base + 720896);           // 12288 B
    unsigned short* h2t   = (unsigned short*)(base + 1048576); // 77 MB bf16
    unsigned short* h1t   = (unsigned short*)d_out;            // h1t, then g (in-place)

    dim3 grid(NBLK, NB), blk(256);
    k_prep<<<dim3(108), blk, 0, stream>>>(w1, w21, w22, Bp);
    k_conv1<<<grid, blk, 0, stream>>>(x, Bp, b1, h1t, part);
    k_gact<<<dim3(147, NB), blk, 0, stream>>>(h1t, part, gn1w, gn1b);
    k_mid<<<grid, blk, 0, stream>>>(h1t, Bp + 18 * 512, Bp + 36 * 512,
                                    b21, b22, h2t, part);
    k_wprep<<<dim3(NB), blk, 0, stream>>>(w3, b3, part, gn2w, gn2b, W3p, biasp);
    k_out<<<grid, blk, 0, stream>>>(h2t, W3p, biasp, (float*)d_out);
}

// Round 9
// 186.366 us; speedup vs baseline: 8.8577x; 1.0852x over previous
//
#include <hip/hip_runtime.h>
#include <math.h>

#define CCH 96
#define HH 112
#define WW 112
#define HWSZ 12544      // 112*112
#define NB 32
#define PIX 64
#define NBLK 196        // tiles per image (14x14 for k_mid, 1D-64 for others)
#define EPSV 1e-5f
#define APITCH 120      // bf16 elems per A-row in conv1 staging LDS
#define TPITCH 72       // bf16 transpose pitch [96 ch][72 pix]
#define TPITCHF 68      // f32 transpose pitch in k_out
#define ROWC 96         // channels per pixel-major row
#define HPITCH 104      // bf16 elems per halo row in k_mid LDS (2-way banks)

typedef __attribute__((ext_vector_type(8))) short bf16x8;
typedef __attribute__((ext_vector_type(4))) float f32x4;
typedef __attribute__((ext_vector_type(8))) unsigned short u16x8;

__device__ __forceinline__ unsigned short f2bf(float f) {
    union { float f; unsigned u; } v; v.f = f;
    unsigned r = v.u + 0x7fffu + ((v.u >> 16) & 1u);   // RTNE
    return (unsigned short)(r >> 16);
}
__device__ __forceinline__ float bf2f(unsigned short h) {
    union { unsigned u; float f; } v; v.u = ((unsigned)h) << 16;
    return v.f;
}
__device__ __forceinline__ unsigned cvt_pk_bf16(float lo, float hi) {
    unsigned r;
    asm("v_cvt_pk_bf16_f32 %0, %1, %2" : "=v"(r) : "v"(lo), "v"(hi));
    return r;
}
// tanh-form GELU via hw exp2/rcp (validated rounds 5-8)
__device__ __forceinline__ float gelu_f(float x) {
    const float K = 2.3022082f;
    float u = x * x;
    float p = x * fmaf(0.044715f, u, 1.0f);
    float e = __builtin_amdgcn_exp2f(p * K);
    float r = __builtin_amdgcn_rcpf(e + 1.0f);
    return x - x * r;
}

__device__ __forceinline__ void block_reduce_write(float sum, float sumsq,
                                                   float* part, int slot) {
    #pragma unroll
    for (int off = 32; off > 0; off >>= 1) {
        sum += __shfl_down(sum, off);
        sumsq += __shfl_down(sumsq, off);
    }
    __shared__ float ls[8];
    const int wid = threadIdx.x >> 6, lane = threadIdx.x & 63;
    if (lane == 0) { ls[wid] = sum; ls[4 + wid] = sumsq; }
    __syncthreads();
    if (threadIdx.x == 0) {
        part[slot * 2 + 0] = ls[0] + ls[1] + ls[2] + ls[3];
        part[slot * 2 + 1] = ls[4] + ls[5] + ls[6] + ls[7];
    }
}

// wave-0 reduce of one sample's 196 partial pairs -> (mu, inv) in shared
__device__ __forceinline__ void stats_reduce(const float* __restrict__ part,
                                             int b, float* sh_mu, float* sh_inv) {
    const int t = threadIdx.x;
    if (t < 64) {
        float s = 0.f, q = 0.f;
        for (int i = t; i < NBLK; i += 64) {
            s += part[(b * NBLK + i) * 2 + 0];
            q += part[(b * NBLK + i) * 2 + 1];
        }
        #pragma unroll
        for (int off = 32; off > 0; off >>= 1) {
            s += __shfl_down(s, off);
            q += __shfl_down(q, off);
        }
        if (t == 0) {
            const float n = (float)CCH * (float)HWSZ;
            const float mu = s / n;
            const float var = q / n - mu * mu;
            *sh_mu = mu;
            *sh_inv = rsqrtf(var + EPSV);
        }
    }
}

// ---- weight prep: fp32 [O][C] -> bf16 fragment layout [m][n0][k0][lane][8] ----
__global__ void k_prep(const float* __restrict__ w1, const float* __restrict__ w21,
                       const float* __restrict__ w22,
                       unsigned short* __restrict__ Bp) {
    const int t = blockIdx.x * 256 + threadIdx.x;   // 3*18*512 = 27648
    if (t >= 3 * 18 * 512) return;
    const int j  = t & 7;
    const int l  = (t >> 3) & 63;
    const int s  = t >> 9;
    const int k0 = s % 3;
    const int n0 = (s / 3) % 6;
    const int m  = s / 18;
    const float* w = (m == 0) ? w1 : (m == 1) ? w21 : w22;
    const int n = n0 * 16 + (l & 15);
    const int k = k0 * 32 + (l >> 4) * 8 + j;
    Bp[t] = f2bf(w[n * CCH + k]);
}

// ---- K1: conv1 (x fp32 channel-major -> h1 bf16 PIXEL-major) + GN1 partials
__global__ __launch_bounds__(256) void k_conv1(
        const float* __restrict__ x, const unsigned short* __restrict__ Bp,
        const float* __restrict__ b1, unsigned short* __restrict__ h1t,
        float* __restrict__ part) {
    __shared__ unsigned short smem[64 * APITCH];   // 15360 B; Tsd (13824 B) reuses
    unsigned short* Asd = smem;
    unsigned short* Tsd = smem;

    const int b = blockIdx.y;
    const int hw0 = blockIdx.x * PIX;
    const int wid = __builtin_amdgcn_readfirstlane(threadIdx.x >> 6);
    const int lane = threadIdx.x & 63;

    const float* xb = x + (size_t)b * CCH * HWSZ + hw0;
    #pragma unroll
    for (int i = 0; i < 24; i += 2) {
        const int c = wid * 24 + i;
        *(unsigned*)&Asd[lane * APITCH + c] =
            cvt_pk_bf16(xb[(size_t)c * HWSZ + lane], xb[(size_t)(c + 1) * HWSZ + lane]);
    }
    __syncthreads();

    bf16x8 a[3];
    const int arow = (wid * 16 + (lane & 15)) * APITCH;
    const int acol = (lane >> 4) * 8;
    #pragma unroll
    for (int k0 = 0; k0 < 3; ++k0)
        a[k0] = *(const bf16x8*)&Asd[arow + k0 * 32 + acol];
    __syncthreads();

    f32x4 acc[6];
    #pragma unroll
    for (int n0 = 0; n0 < 6; ++n0) {
        const float bias = b1[n0 * 16 + (lane & 15)];
        acc[n0] = (f32x4){bias, bias, bias, bias};
        #pragma unroll
        for (int k0 = 0; k0 < 3; ++k0) {
            const bf16x8 bf = *(const bf16x8*)(Bp + (n0 * 3 + k0) * 512 + lane * 8);
            acc[n0] = __builtin_amdgcn_mfma_f32_16x16x32_bf16(a[k0], bf, acc[n0], 0, 0, 0);
        }
    }

    float sum = 0.f, sumsq = 0.f;
    const int p0 = wid * 16 + (lane >> 4) * 4;
    #pragma unroll
    for (int n0 = 0; n0 < 6; ++n0) {
        const int o = n0 * 16 + (lane & 15);
        #pragma unroll
        for (int r = 0; r < 4; ++r) {
            const float v = acc[n0][r];
            sum += v; sumsq += v * v;
        }
        const unsigned lo = cvt_pk_bf16(acc[n0][0], acc[n0][1]);
        const unsigned hi = cvt_pk_bf16(acc[n0][2], acc[n0][3]);
        *(uint2*)&Tsd[o * TPITCH + p0] = make_uint2(lo, hi);
    }
    __syncthreads();

    // cooperative PIXEL-major store: rows hw0..hw0+63, 96 ch each
    unsigned short* ob = h1t + ((size_t)b * HWSZ + hw0) * ROWC;
    #pragma unroll
    for (int it = 0; it < 3; ++it) {
        const int u = threadIdx.x + it * 256;      // 0..767
        const int pr = u / 12;
        const int c16 = (u % 12) * 8;
        unsigned r0 = (unsigned)Tsd[(c16 + 0) * TPITCH + pr] |
                      ((unsigned)Tsd[(c16 + 1) * TPITCH + pr] << 16);
        unsigned r1 = (unsigned)Tsd[(c16 + 2) * TPITCH + pr] |
                      ((unsigned)Tsd[(c16 + 3) * TPITCH + pr] << 16);
        unsigned r2 = (unsigned)Tsd[(c16 + 4) * TPITCH + pr] |
                      ((unsigned)Tsd[(c16 + 5) * TPITCH + pr] << 16);
        unsigned r3 = (unsigned)Tsd[(c16 + 6) * TPITCH + pr] |
                      ((unsigned)Tsd[(c16 + 7) * TPITCH + pr] << 16);
        *(uint4*)&ob[(size_t)pr * ROWC + c16] = make_uint4(r0, r1, r2, r3);
    }
    block_reduce_write(sum, sumsq, part, b * NBLK + blockIdx.x);
}

// ---- K2: fused gn1+gelu (halo-staged) -> 2 GEMMs -> gelu+add -> h2t + GN2 part
// 2D tile: 8x8 pixels, 10x10 halo. part1 in, part2 out (separate buffers!).
__global__ __launch_bounds__(256) void k_mid(
        const unsigned short* __restrict__ h1t,
        const unsigned short* __restrict__ BpA, const unsigned short* __restrict__ BpB,
        const float* __restrict__ b21, const float* __restrict__ b22,
        const float* __restrict__ part1,
        const float* __restrict__ gw, const float* __restrict__ gb,
        unsigned short* __restrict__ h2t, float* __restrict__ part2) {
    __shared__ unsigned short Hs[100 * HPITCH];    // 20800 B; Tsd (13824 B) reuses
    unsigned short* Tsd = Hs;
    __shared__ __align__(16) float ts[CCH];
    __shared__ __align__(16) float th[CCH];
    __shared__ float sh_mu, sh_inv;

    const int b = blockIdx.y;
    const int oy = (blockIdx.x / 14) * 8;          // tile origin
    const int ox = (blockIdx.x % 14) * 8;
    const int tid = threadIdx.x;

    stats_reduce(part1, b, &sh_mu, &sh_inv);
    __syncthreads();
    if (tid < CCH) {
        const float sc = sh_inv * gw[tid];
        ts[tid] = sc;
        th[tid] = gb[tid] - sh_mu * sc;
    }
    __syncthreads();

    // stage 10x10 halo rows (gn1+gelu applied once), zeros for OOB
    const unsigned short* hb1 = h1t + (size_t)b * HWSZ * ROWC;
    #pragma unroll
    for (int it = 0; it < 5; ++it) {
        const int idx = tid + it * 256;            // < 1200 = 100 rows * 12 chunks
        if (idx < 1200) {
            const int r = idx / 12;
            const int c0 = (idx % 12) * 8;
            const int hh = oy - 1 + r / 10;
            const int ww = ox - 1 + r % 10;
            unsigned r0 = 0, r1 = 0, r2 = 0, r3 = 0;
            if ((unsigned)hh < HH && (unsigned)ww < WW) {
                const u16x8 gv = *(const u16x8*)&hb1[((size_t)hh * WW + ww) * ROWC + c0];
                const f32x4 s0 = *(const f32x4*)&ts[c0];
                const f32x4 s1 = *(const f32x4*)&ts[c0 + 4];
                const f32x4 t0 = *(const f32x4*)&th[c0];
                const f32x4 t1 = *(const f32x4*)&th[c0 + 4];
                float f[8];
                #pragma unroll
                for (int j = 0; j < 4; ++j) {
                    f[j]     = gelu_f(fmaf(bf2f(gv[j]),     s0[j], t0[j]));
                    f[j + 4] = gelu_f(fmaf(bf2f(gv[j + 4]), s1[j], t1[j]));
                }
                r0 = cvt_pk_bf16(f[0], f[1]);
                r1 = cvt_pk_bf16(f[2], f[3]);
                r2 = cvt_pk_bf16(f[4], f[5]);
                r3 = cvt_pk_bf16(f[6], f[7]);
            }
            *(uint4*)&Hs[r * HPITCH + c0] = make_uint4(r0, r1, r2, r3);
        }
    }
    __syncthreads();

    const int wid = __builtin_amdgcn_readfirstlane(tid >> 6);
    const int lane = tid & 63;
    const int p = wid * 16 + (lane & 15);          // tile-local pixel 0..63
    const int hr = ((p >> 3) + 1) * 10 + (p & 7) + 1;   // center halo row
    const int acol8 = (lane >> 4) * 8;

    // chunk k0=0: shift +1; k0=1: center; k0=2: shift -1 (all in-LDS, pre-zeroed)
    bf16x8 alr[3], atd[3];
    alr[0] = *(const bf16x8*)&Hs[(hr + 1)  * HPITCH +  0 + acol8];
    alr[1] = *(const bf16x8*)&Hs[hr        * HPITCH + 32 + acol8];
    alr[2] = *(const bf16x8*)&Hs[(hr - 1)  * HPITCH + 64 + acol8];
    atd[0] = *(const bf16x8*)&Hs[(hr + 10) * HPITCH +  0 + acol8];
    atd[1] = alr[1];
    atd[2] = *(const bf16x8*)&Hs[(hr - 10) * HPITCH + 64 + acol8];

    f32x4 accA[6], accB[6];
    #pragma unroll
    for (int n0 = 0; n0 < 6; ++n0) {
        const float biasA = b21[n0 * 16 + (lane & 15)];
        const float biasB = b22[n0 * 16 + (lane & 15)];
        accA[n0] = (f32x4){biasA, biasA, biasA, biasA};
        accB[n0] = (f32x4){biasB, biasB, biasB, biasB};
        #pragma unroll
        for (int k0 = 0; k0 < 3; ++k0) {
            const bf16x8 bA = *(const bf16x8*)(BpA + (n0 * 3 + k0) * 512 + lane * 8);
            const bf16x8 bB = *(const bf16x8*)(BpB + (n0 * 3 + k0) * 512 + lane * 8);
            accA[n0] = __builtin_amdgcn_mfma_f32_16x16x32_bf16(alr[k0], bA, accA[n0], 0, 0, 0);
            accB[n0] = __builtin_amdgcn_mfma_f32_16x16x32_bf16(atd[k0], bB, accB[n0], 0, 0, 0);
        }
    }
    __syncthreads();   // all waves done reading Hs before Tsd overlay

    float sum = 0.f, sumsq = 0.f;
    const int p0 = wid * 16 + (lane >> 4) * 4;
    #pragma unroll
    for (int n0 = 0; n0 < 6; ++n0) {
        const int o = n0 * 16 + (lane & 15);
        float vv[4];
        #pragma unroll
        for (int r = 0; r < 4; ++r) {
            const float v = gelu_f(accA[n0][r]) + gelu_f(accB[n0][r]);
            sum += v; sumsq += v * v;
            vv[r] = v;
        }
        const unsigned lo = cvt_pk_bf16(vv[0], vv[1]);
        const unsigned hi = cvt_pk_bf16(vv[2], vv[3]);
        *(uint2*)&Tsd[o * TPITCH + p0] = make_uint2(lo, hi);
    }
    __syncthreads();

    unsigned short* ob = h2t + (size_t)b * HWSZ * ROWC;
    #pragma unroll
    for (int it = 0; it < 3; ++it) {
        const int u = tid + it * 256;
        const int pr = u / 12;                     // tile-local pixel
        const int c16 = (u % 12) * 8;
        const size_t gp = (size_t)(oy + (pr >> 3)) * WW + ox + (pr & 7);
        unsigned r0 = (unsigned)Tsd[(c16 + 0) * TPITCH + pr] |
                      ((unsigned)Tsd[(c16 + 1) * TPITCH + pr] << 16);
        unsigned r1 = (unsigned)Tsd[(c16 + 2) * TPITCH + pr] |
                      ((unsigned)Tsd[(c16 + 3) * TPITCH + pr] << 16);
        unsigned r2 = (unsigned)Tsd[(c16 + 4) * TPITCH + pr] |
                      ((unsigned)Tsd[(c16 + 5) * TPITCH + pr] << 16);
        unsigned r3 = (unsigned)Tsd[(c16 + 6) * TPITCH + pr] |
                      ((unsigned)Tsd[(c16 + 7) * TPITCH + pr] << 16);
        *(uint4*)&ob[gp * ROWC + c16] = make_uint4(r0, r1, r2, r3);
    }
    block_reduce_write(sum, sumsq, part2, b * NBLK + blockIdx.x);
}

// ---- K3: per-sample GN2 fold into conv3 (stats folded in) ----
__global__ void k_wprep(const float* __restrict__ w3, const float* __restrict__ b3,
                        const float* __restrict__ part2,
                        const float* __restrict__ gw, const float* __restrict__ gb,
                        unsigned short* __restrict__ W3p, float* __restrict__ biasp) {
    const int b = blockIdx.x;
    __shared__ float ts[CCH], th[CCH];
    __shared__ float sh_mu, sh_inv;
    stats_reduce(part2, b, &sh_mu, &sh_inv);
    __syncthreads();
    const int t = threadIdx.x;
    if (t < CCH) {
        const float sc = sh_inv * gw[t];
        ts[t] = sc;
        th[t] = gb[t] - sh_mu * sc;
    }
    __syncthreads();
    unsigned short* Wb = W3p + b * 9216;
    #pragma unroll
    for (int i = 0; i < 36; ++i) {
        const int idx = t + i * 256;               // < 9216
        const int j = idx & 7;
        const int l = (idx >> 3) & 63;
        const int s = idx >> 9;
        const int k0 = s % 3, n0 = s / 3;
        const int n = n0 * 16 + (l & 15);
        const int k = k0 * 32 + (l >> 4) * 8 + j;
        Wb[idx] = f2bf(w3[n * CCH + k] * ts[k]);
    }
    if (t < CCH) {
        float a = b3[t];
        for (int c = 0; c < CCH; ++c) a = fmaf(w3[t * CCH + c], th[c], a);
        biasp[b * CCH + t] = a;
    }
}

// ---- K4: raw frag loads from h2t -> conv3' -> out fp32 channel-major ----
__global__ __launch_bounds__(256) void k_out(
        const unsigned short* __restrict__ h2t, const unsigned short* __restrict__ W3p,
        const float* __restrict__ biasp, float* __restrict__ out) {
    __shared__ float Tf[CCH * TPITCHF];   // 26112 B

    const int b = blockIdx.y;
    const int hw0 = blockIdx.x * PIX;
    const int wid = __builtin_amdgcn_readfirstlane(threadIdx.x >> 6);
    const int lane = threadIdx.x & 63;
    const int prow = hw0 + wid * 16 + (lane & 15);
    const int acol8 = (lane >> 4) * 8;

    const unsigned short* hb = h2t + (size_t)b * HWSZ * ROWC;
    bf16x8 a[3];
    #pragma unroll
    for (int k0 = 0; k0 < 3; ++k0)
        a[k0] = *(const bf16x8*)(hb + (size_t)prow * ROWC + k0 * 32 + acol8);

    const unsigned short* Bb = W3p + b * 9216;
    f32x4 acc[6];
    #pragma unroll
    for (int n0 = 0; n0 < 6; ++n0) {
        const float bias = biasp[b * CCH + n0 * 16 + (lane & 15)];
        acc[n0] = (f32x4){bias, bias, bias, bias};
        #pragma unroll
        for (int k0 = 0; k0 < 3; ++k0) {
            const bf16x8 bf = *(const bf16x8*)(Bb + (n0 * 3 + k0) * 512 + lane * 8);
            acc[n0] = __builtin_amdgcn_mfma_f32_16x16x32_bf16(a[k0], bf, acc[n0], 0, 0, 0);
        }
    }

    const int p0 = wid * 16 + (lane >> 4) * 4;
    #pragma unroll
    for (int n0 = 0; n0 < 6; ++n0) {
        const int o = n0 * 16 + (lane & 15);
        *(f32x4*)&Tf[o * TPITCHF + p0] = acc[n0];
    }
    __syncthreads();

    float* op = out + (size_t)b * CCH * HWSZ + hw0;
    #pragma unroll
    for (int it = 0; it < 6; ++it) {
        const int o = it * 16 + (threadIdx.x >> 4);
        const int p = (threadIdx.x & 15) * 4;
        *(f32x4*)&op[(size_t)o * HWSZ + p] = *(const f32x4*)&Tf[o * TPITCHF + p];
    }
}

extern "C" void kernel_launch(void* const* d_in, const int* in_sizes, int n_in,
                              void* d_out, int out_size, void* d_ws, size_t ws_size,
                              hipStream_t stream) {
    const float* x    = (const float*)d_in[0];
    const float* w1   = (const float*)d_in[1];
    const float* b1   = (const float*)d_in[2];
    const float* w21  = (const float*)d_in[3];
    const float* b21  = (const float*)d_in[4];
    const float* w22  = (const float*)d_in[5];
    const float* b22  = (const float*)d_in[6];
    const float* w3   = (const float*)d_in[7];
    const float* b3   = (const float*)d_in[8];
    const float* gn1w = (const float*)d_in[9];
    const float* gn1b = (const float*)d_in[10];
    const float* gn2w = (const float*)d_in[11];
    const float* gn2b = (const float*)d_in[12];

    char* base = (char*)d_ws;
    unsigned short* Bp    = (unsigned short*)base;             // 55296 B
    float*          part1 = (float*)(base + 73728);            // 50176 B
    float*          part2 = (float*)(base + 123904);           // 50176 B
    unsigned short* W3p   = (unsigned short*)(base + 180224);  // 589824 B
    float*          biasp = (float*)(base + 770048);           // 12288 B
    unsigned short* h2t   = (unsigned short*)(base + 1048576); // 77 MB bf16
    unsigned short* h1t   = (unsigned short*)d_out;            // raw conv1 out (bf16)

    dim3 blk(256);
    k_prep<<<dim3(108), blk, 0, stream>>>(w1, w21, w22, Bp);
    k_conv1<<<dim3(NBLK, NB), blk, 0, stream>>>(x, Bp, b1, h1t, part1);
    k_mid<<<dim3(196, NB), blk, 0, stream>>>(h1t, Bp + 18 * 512, Bp + 36 * 512,
                                             b21, b22, part1, gn1w, gn1b, h2t, part2);
    k_wprep<<<dim3(NB), blk, 0, stream>>>(w3, b3, part2, gn2w, gn2b, W3p, biasp);
    k_out<<<dim3(NBLK, NB), blk, 0, stream>>>(h2t, W3p, biasp, (float*)d_out);
}

// Round 10
// 181.099 us; speedup vs baseline: 9.1153x; 1.0291x over previous
//
#include <hip/hip_runtime.h>
#include <math.h>

#define CCH 96
#define HH 112
#define WW 112
#define HWSZ 12544      // 112*112
#define NB 32
#define PIX 64
#define NBLK 196        // tiles per image (14x14 for k_mid, 1D-64 for others)
#define EPSV 1e-5f
#define APITCH 120      // bf16 elems per A-row in conv1 staging LDS
#define TP2 104         // u16 pitch of [pixel][channel] transpose buffer (52 dw, 2-way)
#define TPITCHF 68      // f32 transpose pitch in k_out
#define ROWC 96         // channels per pixel-major row
#define HPITCH 104      // bf16 elems per halo row in k_mid LDS

typedef __attribute__((ext_vector_type(8))) short bf16x8;
typedef __attribute__((ext_vector_type(4))) float f32x4;
typedef __attribute__((ext_vector_type(8))) unsigned short u16x8;

__device__ __forceinline__ unsigned short f2bf(float f) {
    union { float f; unsigned u; } v; v.f = f;
    unsigned r = v.u + 0x7fffu + ((v.u >> 16) & 1u);   // RTNE
    return (unsigned short)(r >> 16);
}
__device__ __forceinline__ float bf2f(unsigned short h) {
    union { unsigned u; float f; } v; v.u = ((unsigned)h) << 16;
    return v.f;
}
__device__ __forceinline__ unsigned cvt_pk_bf16(float lo, float hi) {
    unsigned r;
    asm("v_cvt_pk_bf16_f32 %0, %1, %2" : "=v"(r) : "v"(lo), "v"(hi));
    return r;
}
// tanh-form GELU via hw exp2/rcp (validated rounds 5-9)
__device__ __forceinline__ float gelu_f(float x) {
    const float K = 2.3022082f;
    float u = x * x;
    float p = x * fmaf(0.044715f, u, 1.0f);
    float e = __builtin_amdgcn_exp2f(p * K);
    float r = __builtin_amdgcn_rcpf(e + 1.0f);
    return x - x * r;
}

__device__ __forceinline__ void block_reduce_write(float sum, float sumsq,
                                                   float* part, int slot) {
    #pragma unroll
    for (int off = 32; off > 0; off >>= 1) {
        sum += __shfl_down(sum, off);
        sumsq += __shfl_down(sumsq, off);
    }
    __shared__ float ls[8];
    const int wid = threadIdx.x >> 6, lane = threadIdx.x & 63;
    if (lane == 0) { ls[wid] = sum; ls[4 + wid] = sumsq; }
    __syncthreads();
    if (threadIdx.x == 0) {
        part[slot * 2 + 0] = ls[0] + ls[1] + ls[2] + ls[3];
        part[slot * 2 + 1] = ls[4] + ls[5] + ls[6] + ls[7];
    }
}

// wave-0 reduce of one sample's 196 partial pairs -> (mu, inv) in shared
__device__ __forceinline__ void stats_reduce(const float* __restrict__ part,
                                             int b, float* sh_mu, float* sh_inv) {
    const int t = threadIdx.x;
    if (t < 64) {
        float s = 0.f, q = 0.f;
        for (int i = t; i < NBLK; i += 64) {
            s += part[(b * NBLK + i) * 2 + 0];
            q += part[(b * NBLK + i) * 2 + 1];
        }
        #pragma unroll
        for (int off = 32; off > 0; off >>= 1) {
            s += __shfl_down(s, off);
            q += __shfl_down(q, off);
        }
        if (t == 0) {
            const float n = (float)CCH * (float)HWSZ;
            const float mu = s / n;
            const float var = q / n - mu * mu;
            *sh_mu = mu;
            *sh_inv = rsqrtf(var + EPSV);
        }
    }
}

// write one C-fragment column (4 pixels x 1 ch) into [pixel][ch] LDS, conflict-free
__device__ __forceinline__ void frag_to_lds_t(unsigned short* Tsd2, int p0, int o,
                                              const f32x4 v) {
    const unsigned lo = cvt_pk_bf16(v[0], v[1]);
    const unsigned hi = cvt_pk_bf16(v[2], v[3]);
    Tsd2[(p0 + 0) * TP2 + o] = (unsigned short)lo;
    Tsd2[(p0 + 1) * TP2 + o] = (unsigned short)(lo >> 16);
    Tsd2[(p0 + 2) * TP2 + o] = (unsigned short)hi;
    Tsd2[(p0 + 3) * TP2 + o] = (unsigned short)(hi >> 16);
}

// ---- weight prep: fp32 [O][C] -> bf16 fragment layout [m][n0][k0][lane][8] ----
__global__ void k_prep(const float* __restrict__ w1, const float* __restrict__ w21,
                       const float* __restrict__ w22,
                       unsigned short* __restrict__ Bp) {
    const int t = blockIdx.x * 256 + threadIdx.x;   // 3*18*512 = 27648
    if (t >= 3 * 18 * 512) return;
    const int j  = t & 7;
    const int l  = (t >> 3) & 63;
    const int s  = t >> 9;
    const int k0 = s % 3;
    const int n0 = (s / 3) % 6;
    const int m  = s / 18;
    const float* w = (m == 0) ? w1 : (m == 1) ? w21 : w22;
    const int n = n0 * 16 + (l & 15);
    const int k = k0 * 32 + (l >> 4) * 8 + j;
    Bp[t] = f2bf(w[n * CCH + k]);
}

// ---- K1: conv1 (x fp32 channel-major -> h1 bf16 PIXEL-major) + GN1 partials
__global__ __launch_bounds__(256) void k_conv1(
        const float* __restrict__ x, const unsigned short* __restrict__ Bp,
        const float* __restrict__ b1, unsigned short* __restrict__ h1t,
        float* __restrict__ part) {
    __shared__ unsigned short smem[64 * APITCH];   // 15360 B; Tsd2 (13312 B) reuses
    unsigned short* Asd = smem;
    unsigned short* Tsd2 = smem;

    const int b = blockIdx.y;
    const int hw0 = blockIdx.x * PIX;
    const int wid = __builtin_amdgcn_readfirstlane(threadIdx.x >> 6);
    const int lane = threadIdx.x & 63;

    const float* xb = x + (size_t)b * CCH * HWSZ + hw0;
    #pragma unroll
    for (int i = 0; i < 24; i += 2) {
        const int c = wid * 24 + i;
        *(unsigned*)&Asd[lane * APITCH + c] =
            cvt_pk_bf16(xb[(size_t)c * HWSZ + lane], xb[(size_t)(c + 1) * HWSZ + lane]);
    }
    __syncthreads();

    bf16x8 a[3];
    const int arow = (wid * 16 + (lane & 15)) * APITCH;
    const int acol = (lane >> 4) * 8;
    #pragma unroll
    for (int k0 = 0; k0 < 3; ++k0)
        a[k0] = *(const bf16x8*)&Asd[arow + k0 * 32 + acol];
    __syncthreads();

    f32x4 acc[6];
    #pragma unroll
    for (int n0 = 0; n0 < 6; ++n0) {
        const float bias = b1[n0 * 16 + (lane & 15)];
        acc[n0] = (f32x4){bias, bias, bias, bias};
        #pragma unroll
        for (int k0 = 0; k0 < 3; ++k0) {
            const bf16x8 bf = *(const bf16x8*)(Bp + (n0 * 3 + k0) * 512 + lane * 8);
            acc[n0] = __builtin_amdgcn_mfma_f32_16x16x32_bf16(a[k0], bf, acc[n0], 0, 0, 0);
        }
    }

    float sum = 0.f, sumsq = 0.f;
    const int p0 = wid * 16 + (lane >> 4) * 4;
    #pragma unroll
    for (int n0 = 0; n0 < 6; ++n0) {
        const int o = n0 * 16 + (lane & 15);
        #pragma unroll
        for (int r = 0; r < 4; ++r) {
            const float v = acc[n0][r];
            sum += v; sumsq += v * v;
        }
        frag_to_lds_t(Tsd2, p0, o, acc[n0]);
    }
    __syncthreads();

    // cooperative PIXEL-major store: rows hw0..hw0+63, 96 ch each (uint4 reads)
    unsigned short* ob = h1t + ((size_t)b * HWSZ + hw0) * ROWC;
    #pragma unroll
    for (int it = 0; it < 3; ++it) {
        const int u = threadIdx.x + it * 256;      // 0..767
        const int pr = u / 12;
        const int c16 = (u % 12) * 8;
        *(uint4*)&ob[(size_t)pr * ROWC + c16] = *(const uint4*)&Tsd2[pr * TP2 + c16];
    }
    block_reduce_write(sum, sumsq, part, b * NBLK + blockIdx.x);
}

// ---- K2: fused gn1+gelu (halo-staged) -> 2 GEMMs -> gelu+add -> h2t + GN2 part
// 2D tile: 8x8 pixels, 10x10 halo. part1 in, part2 out (separate buffers!).
__global__ __launch_bounds__(256) void k_mid(
        const unsigned short* __restrict__ h1t,
        const unsigned short* __restrict__ BpA, const unsigned short* __restrict__ BpB,
        const float* __restrict__ b21, const float* __restrict__ b22,
        const float* __restrict__ part1,
        const float* __restrict__ gw, const float* __restrict__ gb,
        unsigned short* __restrict__ h2t, float* __restrict__ part2) {
    __shared__ unsigned short Hs[100 * HPITCH];    // 20800 B; Tsd2 (13312 B) reuses
    unsigned short* Tsd2 = Hs;
    __shared__ __align__(16) float ts[CCH];
    __shared__ __align__(16) float th[CCH];
    __shared__ float sh_mu, sh_inv;

    const int b = blockIdx.y;
    const int oy = (blockIdx.x / 14) * 8;          // tile origin
    const int ox = (blockIdx.x % 14) * 8;
    const int tid = threadIdx.x;

    stats_reduce(part1, b, &sh_mu, &sh_inv);
    __syncthreads();
    if (tid < CCH) {
        const float sc = sh_inv * gw[tid];
        ts[tid] = sc;
        th[tid] = gb[tid] - sh_mu * sc;
    }
    __syncthreads();

    // stage 10x10 halo rows (gn1+gelu applied once), zeros for OOB
    const unsigned short* hb1 = h1t + (size_t)b * HWSZ * ROWC;
    #pragma unroll
    for (int it = 0; it < 5; ++it) {
        const int idx = tid + it * 256;            // < 1200 = 100 rows * 12 chunks
        if (idx < 1200) {
            const int r = idx / 12;
            const int c0 = (idx % 12) * 8;
            const int hh = oy - 1 + r / 10;
            const int ww = ox - 1 + r % 10;
            unsigned r0 = 0, r1 = 0, r2 = 0, r3 = 0;
            if ((unsigned)hh < HH && (unsigned)ww < WW) {
                const u16x8 gv = *(const u16x8*)&hb1[((size_t)hh * WW + ww) * ROWC + c0];
                const f32x4 s0 = *(const f32x4*)&ts[c0];
                const f32x4 s1 = *(const f32x4*)&ts[c0 + 4];
                const f32x4 t0 = *(const f32x4*)&th[c0];
                const f32x4 t1 = *(const f32x4*)&th[c0 + 4];
                float f[8];
                #pragma unroll
                for (int j = 0; j < 4; ++j) {
                    f[j]     = gelu_f(fmaf(bf2f(gv[j]),     s0[j], t0[j]));
                    f[j + 4] = gelu_f(fmaf(bf2f(gv[j + 4]), s1[j], t1[j]));
                }
                r0 = cvt_pk_bf16(f[0], f[1]);
                r1 = cvt_pk_bf16(f[2], f[3]);
                r2 = cvt_pk_bf16(f[4], f[5]);
                r3 = cvt_pk_bf16(f[6], f[7]);
            }
            *(uint4*)&Hs[r * HPITCH + c0] = make_uint4(r0, r1, r2, r3);
        }
    }
    __syncthreads();

    const int wid = __builtin_amdgcn_readfirstlane(tid >> 6);
    const int lane = tid & 63;
    const int p = wid * 16 + (lane & 15);          // tile-local pixel 0..63
    const int hr = ((p >> 3) + 1) * 10 + (p & 7) + 1;   // center halo row
    const int acol8 = (lane >> 4) * 8;

    // chunk k0=0: shift +1; k0=1: center; k0=2: shift -1 (all in-LDS, pre-zeroed)
    bf16x8 alr[3], atd[3];
    alr[0] = *(const bf16x8*)&Hs[(hr + 1)  * HPITCH +  0 + acol8];
    alr[1] = *(const bf16x8*)&Hs[hr        * HPITCH + 32 + acol8];
    alr[2] = *(const bf16x8*)&Hs[(hr - 1)  * HPITCH + 64 + acol8];
    atd[0] = *(const bf16x8*)&Hs[(hr + 10) * HPITCH +  0 + acol8];
    atd[1] = alr[1];
    atd[2] = *(const bf16x8*)&Hs[(hr - 10) * HPITCH + 64 + acol8];

    f32x4 accA[6], accB[6];
    #pragma unroll
    for (int n0 = 0; n0 < 6; ++n0) {
        const float biasA = b21[n0 * 16 + (lane & 15)];
        const float biasB = b22[n0 * 16 + (lane & 15)];
        accA[n0] = (f32x4){biasA, biasA, biasA, biasA};
        accB[n0] = (f32x4){biasB, biasB, biasB, biasB};
        #pragma unroll
        for (int k0 = 0; k0 < 3; ++k0) {
            const bf16x8 bA = *(const bf16x8*)(BpA + (n0 * 3 + k0) * 512 + lane * 8);
            const bf16x8 bB = *(const bf16x8*)(BpB + (n0 * 3 + k0) * 512 + lane * 8);
            accA[n0] = __builtin_amdgcn_mfma_f32_16x16x32_bf16(alr[k0], bA, accA[n0], 0, 0, 0);
            accB[n0] = __builtin_amdgcn_mfma_f32_16x16x32_bf16(atd[k0], bB, accB[n0], 0, 0, 0);
        }
    }
    __syncthreads();   // all waves done reading Hs before Tsd2 overlay

    float sum = 0.f, sumsq = 0.f;
    const int p0 = wid * 16 + (lane >> 4) * 4;
    #pragma unroll
    for (int n0 = 0; n0 < 6; ++n0) {
        const int o = n0 * 16 + (lane & 15);
        f32x4 vv;
        #pragma unroll
        for (int r = 0; r < 4; ++r) {
            const float v = gelu_f(accA[n0][r]) + gelu_f(accB[n0][r]);
            sum += v; sumsq += v * v;
            vv[r] = v;
        }
        frag_to_lds_t(Tsd2, p0, o, vv);
    }
    __syncthreads();

    unsigned short* ob = h2t + (size_t)b * HWSZ * ROWC;
    #pragma unroll
    for (int it = 0; it < 3; ++it) {
        const int u = tid + it * 256;
        const int pr = u / 12;                     // tile-local pixel
        const int c16 = (u % 12) * 8;
        const size_t gp = (size_t)(oy + (pr >> 3)) * WW + ox + (pr & 7);
        *(uint4*)&ob[gp * ROWC + c16] = *(const uint4*)&Tsd2[pr * TP2 + c16];
    }
    block_reduce_write(sum, sumsq, part2, b * NBLK + blockIdx.x);
}

// ---- K3: per-sample GN2 fold into conv3 (stats folded in) ----
__global__ void k_wprep(const float* __restrict__ w3, const float* __restrict__ b3,
                        const float* __restrict__ part2,
                        const float* __restrict__ gw, const float* __restrict__ gb,
                        unsigned short* __restrict__ W3p, float* __restrict__ biasp) {
    const int b = blockIdx.x;
    __shared__ float ts[CCH], th[CCH];
    __shared__ float sh_mu, sh_inv;
    stats_reduce(part2, b, &sh_mu, &sh_inv);
    __syncthreads();
    const int t = threadIdx.x;
    if (t < CCH) {
        const float sc = sh_inv * gw[t];
        ts[t] = sc;
        th[t] = gb[t] - sh_mu * sc;
    }
    __syncthreads();
    unsigned short* Wb = W3p + b * 9216;
    #pragma unroll
    for (int i = 0; i < 36; ++i) {
        const int idx = t + i * 256;               // < 9216
        const int j = idx & 7;
        const int l = (idx >> 3) & 63;
        const int s = idx >> 9;
        const int k0 = s % 3, n0 = s / 3;
        const int n = n0 * 16 + (l & 15);
        const int k = k0 * 32 + (l >> 4) * 8 + j;
        Wb[idx] = f2bf(w3[n * CCH + k] * ts[k]);
    }
    if (t < CCH) {
        float a = b3[t];
        for (int c = 0; c < CCH; ++c) a = fmaf(w3[t * CCH + c], th[c], a);
        biasp[b * CCH + t] = a;
    }
}

// ---- K4: raw frag loads from h2t -> conv3' -> out fp32 channel-major ----
__global__ __launch_bounds__(256) void k_out(
        const unsigned short* __restrict__ h2t, const unsigned short* __restrict__ W3p,
        const float* __restrict__ biasp, float* __restrict__ out) {
    __shared__ float Tf[CCH * TPITCHF];   // 26112 B

    const int b = blockIdx.y;
    const int hw0 = blockIdx.x * PIX;
    const int wid = __builtin_amdgcn_readfirstlane(threadIdx.x >> 6);
    const int lane = threadIdx.x & 63;
    const int prow = hw0 + wid * 16 + (lane & 15);
    const int acol8 = (lane >> 4) * 8;

    const unsigned short* hb = h2t + (size_t)b * HWSZ * ROWC;
    bf16x8 a[3];
    #pragma unroll
    for (int k0 = 0; k0 < 3; ++k0)
        a[k0] = *(const bf16x8*)(hb + (size_t)prow * ROWC + k0 * 32 + acol8);

    const unsigned short* Bb = W3p + b * 9216;
    f32x4 acc[6];
    #pragma unroll
    for (int n0 = 0; n0 < 6; ++n0) {
        const float bias = biasp[b * CCH + n0 * 16 + (lane & 15)];
        acc[n0] = (f32x4){bias, bias, bias, bias};
        #pragma unroll
        for (int k0 = 0; k0 < 3; ++k0) {
            const bf16x8 bf = *(const bf16x8*)(Bb + (n0 * 3 + k0) * 512 + lane * 8);
            acc[n0] = __builtin_amdgcn_mfma_f32_16x16x32_bf16(a[k0], bf, acc[n0], 0, 0, 0);
        }
    }

    const int p0 = wid * 16 + (lane >> 4) * 4;
    #pragma unroll
    for (int n0 = 0; n0 < 6; ++n0) {
        const int o = n0 * 16 + (lane & 15);
        *(f32x4*)&Tf[o * TPITCHF + p0] = acc[n0];
    }
    __syncthreads();

    float* op = out + (size_t)b * CCH * HWSZ + hw0;
    #pragma unroll
    for (int it = 0; it < 6; ++it) {
        const int o = it * 16 + (threadIdx.x >> 4);
        const int p = (threadIdx.x & 15) * 4;
        *(f32x4*)&op[(size_t)o * HWSZ + p] = *(const f32x4*)&Tf[o * TPITCHF + p];
    }
}

extern "C" void kernel_launch(void* const* d_in, const int* in_sizes, int n_in,
                              void* d_out, int out_size, void* d_ws, size_t ws_size,
                              hipStream_t stream) {
    const float* x    = (const float*)d_in[0];
    const float* w1   = (const float*)d_in[1];
    const float* b1   = (const float*)d_in[2];
    const float* w21  = (const float*)d_in[3];
    const float* b21  = (const float*)d_in[4];
    const float* w22  = (const float*)d_in[5];
    const float* b22  = (const float*)d_in[6];
    const float* w3   = (const float*)d_in[7];
    const float* b3   = (const float*)d_in[8];
    const float* gn1w = (const float*)d_in[9];
    const float* gn1b = (const float*)d_in[10];
    const float* gn2w = (const float*)d_in[11];
    const float* gn2b = (const float*)d_in[12];

    char* base = (char*)d_ws;
    unsigned short* Bp    = (unsigned short*)base;             // 55296 B
    float*          part1 = (float*)(base + 73728);            // 50176 B
    float*          part2 = (float*)(base + 123904);           // 50176 B
    unsigned short* W3p   = (unsigned short*)(base + 180224);  // 589824 B
    float*          biasp = (float*)(base + 770048);           // 12288 B
    unsigned short* h2t   = (unsigned short*)(base + 1048576); // 77 MB bf16
    unsigned short* h1t   = (unsigned short*)d_out;            // raw conv1 out (bf16)

    dim3 blk(256);
    k_prep<<<dim3(108), blk, 0, stream>>>(w1, w21, w22, Bp);
    k_conv1<<<dim3(NBLK, NB), blk, 0, stream>>>(x, Bp, b1, h1t, part1);
    k_mid<<<dim3(196, NB), blk, 0, stream>>>(h1t, Bp + 18 * 512, Bp + 36 * 512,
                                             b21, b22, part1, gn1w, gn1b, h2t, part2);
    k_wprep<<<dim3(NB), blk, 0, stream>>>(w3, b3, part2, gn2w, gn2b, W3p, biasp);
    k_out<<<dim3(NBLK, NB), blk, 0, stream>>>(h2t, W3p, biasp, (float*)d_out);
}